// Round 8
// baseline (1774.478 us; speedup 1.0000x reference)
//
#include <hip/hip_runtime.h>

typedef __attribute__((ext_vector_type(8))) short short8v;
typedef __attribute__((ext_vector_type(4))) float f32x4;
typedef __attribute__((ext_vector_type(16))) float f32x16;

static constexpr int Bt = 32;
static constexpr int SEQ = 336, PRED = 336, CIN = 7, ALLT = 672;
static constexpr int DM = 64, NFFT = 64, HOP = 8, NF = 85;
static constexpr int MARK = 4;
static constexpr float INV3 = 1.0f / 3.0f;

__device__ inline short f2bf(float v) {
    unsigned u = __float_as_uint(v);
    u += 0x7fffu + ((u >> 16) & 1u);   // round-to-nearest-even
    return (short)(u >> 16);
}
__device__ inline float bf2f(short h) {
    return __uint_as_float(((unsigned)(unsigned short)h) << 16);
}
__device__ inline int pack2(float r, float i) {
    return ((int)(unsigned short)f2bf(r)) | (((int)(unsigned short)f2bf(i)) << 16);
}
__device__ inline void async16(const int* g, short* l) {
    __builtin_amdgcn_global_load_lds(
        (const __attribute__((address_space(1))) unsigned int*)g,
        (__attribute__((address_space(3))) unsigned int*)l, 16, 0, 0);
}

// ---------------- K1: per (b,c) mean / std over time ----------------
__global__ __launch_bounds__(64) void k_stats(const float* __restrict__ x,
                                              float* __restrict__ mean,
                                              float* __restrict__ stdv) {
    int bc = blockIdx.x;              // b*7+c
    int b = bc / CIN, c = bc % CIN;
    int lane = threadIdx.x;
    float s = 0.f, s2 = 0.f;
    for (int t = lane; t < SEQ; t += 64) {
        float v = x[(b * SEQ + t) * CIN + c];
        s += v; s2 += v * v;
    }
    for (int m = 32; m >= 1; m >>= 1) { s += __shfl_xor(s, m); s2 += __shfl_xor(s2, m); }
    if (lane == 0) {
        float mu = s / SEQ;
        float var = s2 / SEQ - mu * mu;
        mean[bc] = mu;
        stdv[bc] = sqrtf(var + 1e-5f);
    }
}

// ---------------- K2: embedding (token conv + temporal + PE) ----------------
__global__ __launch_bounds__(256) void k_embed(const float* __restrict__ x,
                                               const float* __restrict__ mark,
                                               const float* __restrict__ tok_w,
                                               const float* __restrict__ temp_w,
                                               const float* __restrict__ mean,
                                               const float* __restrict__ stdv,
                                               float* __restrict__ enc0) {
    int i = blockIdx.x * 256 + threadIdx.x;
    if (i >= Bt * SEQ * DM) return;
    int d = i & 63;
    int t = (i >> 6) % SEQ;
    int b = i / (SEQ * DM);
    float val = 0.f;
    for (int c = 0; c < CIN; ++c) {
        float mu = mean[b * CIN + c];
        float is = 1.f / stdv[b * CIN + c];
        for (int j = 0; j < 3; ++j) {
            int tt = t + j - 1;
            if (tt < 0) tt += SEQ;
            if (tt >= SEQ) tt -= SEQ;
            float xv = (x[(b * SEQ + tt) * CIN + c] - mu) * is;
            val += xv * tok_w[(d * CIN + c) * 3 + j];
        }
    }
    float mk = 0.f;
    for (int m = 0; m < MARK; ++m) mk += mark[(b * SEQ + t) * MARK + m] * temp_w[d * MARK + m];
    float div = expf(-(float)(d & ~1) * (9.210340371976184f / (float)DM));
    float arg = (float)t * div;
    float pe = (d & 1) ? cosf(arg) : sinf(arg);
    enc0[i] = val + mk + pe;
}

// ---------------- K3: predict_linear (time 336 -> 672), LDS-blocked ----------------
// grid = 32 b x 14 a-tiles (48 a). Each thread: 3a x 4d outputs.
__global__ __launch_bounds__(256) void k_plin2(const float* __restrict__ enc0,
                                               const float* __restrict__ pl_w,
                                               const float* __restrict__ pl_b,
                                               float* __restrict__ enc) {
    __shared__ float Et[56 * 64];     // [t][d]
    __shared__ float Wt[56 * 49];     // [t][a], pad 49
    int blk = blockIdx.x;
    int b = blk / 14, at = blk % 14;
    int abase = at * 48;
    int tid = threadIdx.x;
    int a0 = (tid & 15) * 3;
    int d0 = (tid >> 4) * 4;
    float acc[3][4];
#pragma unroll
    for (int q = 0; q < 3; ++q)
#pragma unroll
        for (int r = 0; r < 4; ++r) acc[q][r] = 0.f;
    for (int tc = 0; tc < 6; ++tc) {
        if (tc) __syncthreads();
        for (int i = tid; i < 56 * 64; i += 256)
            Et[i] = enc0[((size_t)b * SEQ + tc * 56) * DM + i];
        for (int i = tid; i < 48 * 56; i += 256) {
            int r = i / 56, c = i - r * 56;
            Wt[c * 49 + r] = pl_w[(size_t)(abase + r) * SEQ + tc * 56 + c];
        }
        __syncthreads();
#pragma unroll 4
        for (int t = 0; t < 56; ++t) {
            float4 e = *(const float4*)&Et[t * 64 + d0];
            float w0 = Wt[t * 49 + a0];
            float w1 = Wt[t * 49 + a0 + 1];
            float w2 = Wt[t * 49 + a0 + 2];
            acc[0][0] += w0 * e.x; acc[0][1] += w0 * e.y;
            acc[0][2] += w0 * e.z; acc[0][3] += w0 * e.w;
            acc[1][0] += w1 * e.x; acc[1][1] += w1 * e.y;
            acc[1][2] += w1 * e.z; acc[1][3] += w1 * e.w;
            acc[2][0] += w2 * e.x; acc[2][1] += w2 * e.y;
            acc[2][2] += w2 * e.z; acc[2][3] += w2 * e.w;
        }
    }
#pragma unroll
    for (int q = 0; q < 3; ++q) {
        int a = abase + a0 + q;
        float bias = pl_b[a];
        float4 o = {acc[q][0] + bias, acc[q][1] + bias, acc[q][2] + bias, acc[q][3] + bias};
        *(float4*)&enc[((size_t)b * ALLT + a) * DM + d0] = o;
    }
}

// ---------------- K4: STFT (reflect pad + hann + DFT64, ortho) ----------------
__global__ __launch_bounds__(256) void k_stft(const float* __restrict__ enc, int b0,
                                              float* __restrict__ Sr, float* __restrict__ Si) {
    __shared__ float xp[ALLT + NFFT];   // 736
    __shared__ float twc[64], tws[64];
    __shared__ float xw[NF * 65];       // padded ld=65 (bank-conflict-free)
    int bl = blockIdx.x >> 6;
    int n = blockIdx.x & 63;
    int bg = b0 + bl;
    int t = threadIdx.x;
    for (int i = t; i < ALLT + NFFT; i += 256) {
        int j = i - 32;
        if (j < 0) j = -j;
        if (j > ALLT - 1) j = 2 * (ALLT - 1) - j;
        xp[i] = enc[((size_t)bg * ALLT + j) * DM + n];
    }
    if (t < 64) {
        float ang = (6.283185307179586f / 64.f) * (float)t;
        twc[t] = cosf(ang);
        tws[t] = sinf(ang);
    }
    __syncthreads();
    for (int i = t; i < NF * NFFT; i += 256) {
        int f = i >> 6, tt = i & 63;
        float win = (0.5f - 0.5f * twc[tt]) * 0.125f;  // hann * 1/sqrt(64)
        xw[f * 65 + tt] = xp[f * HOP + tt] * win;
    }
    __syncthreads();
    size_t base = (size_t)(bl * 64 + n) * NFFT * NF;
    for (int i = t; i < NFFT * NF; i += 256) {
        int k = i / NF, f = i % NF;
        float ar = 0.f, ai = 0.f;
        for (int tt = 0; tt < 64; ++tt) {
            float v = xw[f * 65 + tt];
            int m = (k * tt) & 63;
            ar += v * twc[m];
            ai -= v * tws[m];
        }
        Sr[base + (size_t)k * NF + f] = ar;
        Si[base + (size_t)k * NF + f] = ai;
    }
}

// ---------------- K5: qk + sigmoid gate + a = g S, via split-bf16 MFMA ----------------
// Writes A as fp32 (Ar,Ai) for c0 AND as packed bf16 Apk[bl][n/4][x][f][n%4] for the convs.
__global__ __launch_bounds__(256) void k_qka_m(const float* __restrict__ Sr,
                                               const float* __restrict__ Si,
                                               float* __restrict__ Ar,
                                               float* __restrict__ Ai,
                                               int* __restrict__ Apk) {
    __shared__ __align__(16) short L[54272];  // 108,544 B
    constexpr int SRH = 0, SIH = 6656, SRL = 13312, SIL = 19968;        // [64][104]
    constexpr int STRH = 26624, STRL = 33536, STIH = 40448, STIL = 47360;  // [96][72]
    constexpr int GRH = 0, GRL = 4608, GIH = 9216, GIL = 13824;         // [64][72] overlay
    int bn = blockIdx.x;
    int tid = threadIdx.x;
    int lane = tid & 63, w = tid >> 6;
    int l31 = lane & 31, kg = lane >> 5;
    int bl = bn >> 6, n = bn & 63;
    size_t base = (size_t)bn * (64 * 85);
    size_t pkbase = ((size_t)(bl * 16 + (n >> 2)) * 64) * 85 * 4 + (n & 3);

    for (int j = tid; j < 64 * 11; j += 256) {
        int x = j / 11, f = 85 + j % 11;
        L[SRH + x * 104 + f] = 0; L[SIH + x * 104 + f] = 0;
        L[SRL + x * 104 + f] = 0; L[SIL + x * 104 + f] = 0;
    }
    for (int j = tid; j < 11 * 72; j += 256) {
        int f = 85 + j / 72, y = j % 72;
        L[STRH + f * 72 + y] = 0; L[STRL + f * 72 + y] = 0;
        L[STIH + f * 72 + y] = 0; L[STIL + f * 72 + y] = 0;
    }
    for (int i = tid; i < 64 * 85; i += 256) {
        int x = i / 85, f = i - x * 85;
        float vr = Sr[base + i], vi = Si[base + i];
        short rh = f2bf(vr); short rl = f2bf(vr - bf2f(rh));
        short ih = f2bf(vi); short il = f2bf(vi - bf2f(ih));
        L[SRH + x * 104 + f] = rh; L[SRL + x * 104 + f] = rl;
        L[SIH + x * 104 + f] = ih; L[SIL + x * 104 + f] = il;
        L[STRH + f * 72 + x] = rh; L[STRL + f * 72 + x] = rl;
        L[STIH + f * 72 + x] = ih; L[STIL + f * 72 + x] = il;
    }
    __syncthreads();

    int mh = w >> 1, nh = w & 1;
    f32x16 P, Q, R;
#pragma unroll
    for (int r = 0; r < 16; ++r) { P[r] = 0.f; Q[r] = 0.f; R[r] = 0.f; }
#pragma unroll
    for (int f0 = 0; f0 < 96; f0 += 16) {
        int ka = f0 + kg * 8;
        int ra = (mh * 32 + l31) * 104 + ka;
        int rb = (nh * 32 + l31) * 104 + ka;
        short8v a_rh = *(const short8v*)&L[SRH + ra];
        short8v a_rl = *(const short8v*)&L[SRL + ra];
        short8v a_ih = *(const short8v*)&L[SIH + ra];
        short8v a_il = *(const short8v*)&L[SIL + ra];
        short8v b_rh = *(const short8v*)&L[SRH + rb];
        short8v b_rl = *(const short8v*)&L[SRL + rb];
        short8v b_ih = *(const short8v*)&L[SIH + rb];
        short8v b_il = *(const short8v*)&L[SIL + rb];
        P = __builtin_amdgcn_mfma_f32_32x32x16_bf16(a_rh, b_rh, P, 0, 0, 0);
        P = __builtin_amdgcn_mfma_f32_32x32x16_bf16(a_rl, b_rh, P, 0, 0, 0);
        P = __builtin_amdgcn_mfma_f32_32x32x16_bf16(a_rh, b_rl, P, 0, 0, 0);
        Q = __builtin_amdgcn_mfma_f32_32x32x16_bf16(a_ih, b_ih, Q, 0, 0, 0);
        Q = __builtin_amdgcn_mfma_f32_32x32x16_bf16(a_il, b_ih, Q, 0, 0, 0);
        Q = __builtin_amdgcn_mfma_f32_32x32x16_bf16(a_ih, b_il, Q, 0, 0, 0);
        R = __builtin_amdgcn_mfma_f32_32x32x16_bf16(a_rh, b_ih, R, 0, 0, 0);
        R = __builtin_amdgcn_mfma_f32_32x32x16_bf16(a_rl, b_ih, R, 0, 0, 0);
        R = __builtin_amdgcn_mfma_f32_32x32x16_bf16(a_rh, b_il, R, 0, 0, 0);
        R = __builtin_amdgcn_mfma_f32_32x32x16_bf16(a_ih, b_rh, R, 0, 0, 0);
        R = __builtin_amdgcn_mfma_f32_32x32x16_bf16(a_il, b_rh, R, 0, 0, 0);
        R = __builtin_amdgcn_mfma_f32_32x32x16_bf16(a_ih, b_rl, R, 0, 0, 0);
    }
    __syncthreads();

    {
        int y = nh * 32 + l31;
#pragma unroll
        for (int r = 0; r < 16; ++r) {
            int x = mh * 32 + (r & 3) + 8 * (r >> 2) + 4 * kg;
            float gr = 1.f / (1.f + __expf(-(P[r] - Q[r])));
            float gi = 1.f / (1.f + __expf(-R[r]));
            short gh = f2bf(gr); short gl = f2bf(gr - bf2f(gh));
            short jh = f2bf(gi); short jl = f2bf(gi - bf2f(jh));
            L[GRH + x * 72 + y] = gh; L[GRL + x * 72 + y] = gl;
            L[GIH + x * 72 + y] = jh; L[GIL + x * 72 + y] = jl;
        }
    }
    __syncthreads();

    int mg = w >> 1;
    int mtA = (mg == 0) ? 0 : 2;
    f32x16 u1A, u2A, u3A, u1B, u2B, u3B;
#pragma unroll
    for (int r = 0; r < 16; ++r) {
        u1A[r] = 0.f; u2A[r] = 0.f; u3A[r] = 0.f;
        u1B[r] = 0.f; u2B[r] = 0.f; u3B[r] = 0.f;
    }
#pragma unroll
    for (int y0 = 0; y0 < 64; y0 += 16) {
        int kb = y0 + kg * 8;
        int gb = (nh * 32 + l31) * 72 + kb;
        short8v bgrh = *(const short8v*)&L[GRH + gb];
        short8v bgrl = *(const short8v*)&L[GRL + gb];
        short8v bgih = *(const short8v*)&L[GIH + gb];
        short8v bgil = *(const short8v*)&L[GIL + gb];
        {
            int sa = (mtA * 32 + l31) * 72 + kb;
            short8v arh = *(const short8v*)&L[STRH + sa];
            short8v arl = *(const short8v*)&L[STRL + sa];
            short8v aih = *(const short8v*)&L[STIH + sa];
            short8v ail = *(const short8v*)&L[STIL + sa];
            u1A = __builtin_amdgcn_mfma_f32_32x32x16_bf16(arh, bgrh, u1A, 0, 0, 0);
            u1A = __builtin_amdgcn_mfma_f32_32x32x16_bf16(arl, bgrh, u1A, 0, 0, 0);
            u1A = __builtin_amdgcn_mfma_f32_32x32x16_bf16(arh, bgrl, u1A, 0, 0, 0);
            u2A = __builtin_amdgcn_mfma_f32_32x32x16_bf16(aih, bgih, u2A, 0, 0, 0);
            u2A = __builtin_amdgcn_mfma_f32_32x32x16_bf16(ail, bgih, u2A, 0, 0, 0);
            u2A = __builtin_amdgcn_mfma_f32_32x32x16_bf16(aih, bgil, u2A, 0, 0, 0);
            u3A = __builtin_amdgcn_mfma_f32_32x32x16_bf16(aih, bgrh, u3A, 0, 0, 0);
            u3A = __builtin_amdgcn_mfma_f32_32x32x16_bf16(ail, bgrh, u3A, 0, 0, 0);
            u3A = __builtin_amdgcn_mfma_f32_32x32x16_bf16(aih, bgrl, u3A, 0, 0, 0);
            u3A = __builtin_amdgcn_mfma_f32_32x32x16_bf16(arh, bgih, u3A, 0, 0, 0);
            u3A = __builtin_amdgcn_mfma_f32_32x32x16_bf16(arl, bgih, u3A, 0, 0, 0);
            u3A = __builtin_amdgcn_mfma_f32_32x32x16_bf16(arh, bgil, u3A, 0, 0, 0);
        }
        if (mg == 0) {
            int sa = (1 * 32 + l31) * 72 + kb;
            short8v arh = *(const short8v*)&L[STRH + sa];
            short8v arl = *(const short8v*)&L[STRL + sa];
            short8v aih = *(const short8v*)&L[STIH + sa];
            short8v ail = *(const short8v*)&L[STIL + sa];
            u1B = __builtin_amdgcn_mfma_f32_32x32x16_bf16(arh, bgrh, u1B, 0, 0, 0);
            u1B = __builtin_amdgcn_mfma_f32_32x32x16_bf16(arl, bgrh, u1B, 0, 0, 0);
            u1B = __builtin_amdgcn_mfma_f32_32x32x16_bf16(arh, bgrl, u1B, 0, 0, 0);
            u2B = __builtin_amdgcn_mfma_f32_32x32x16_bf16(aih, bgih, u2B, 0, 0, 0);
            u2B = __builtin_amdgcn_mfma_f32_32x32x16_bf16(ail, bgih, u2B, 0, 0, 0);
            u2B = __builtin_amdgcn_mfma_f32_32x32x16_bf16(aih, bgil, u2B, 0, 0, 0);
            u3B = __builtin_amdgcn_mfma_f32_32x32x16_bf16(aih, bgrh, u3B, 0, 0, 0);
            u3B = __builtin_amdgcn_mfma_f32_32x32x16_bf16(ail, bgrh, u3B, 0, 0, 0);
            u3B = __builtin_amdgcn_mfma_f32_32x32x16_bf16(aih, bgrl, u3B, 0, 0, 0);
            u3B = __builtin_amdgcn_mfma_f32_32x32x16_bf16(arh, bgih, u3B, 0, 0, 0);
            u3B = __builtin_amdgcn_mfma_f32_32x32x16_bf16(arl, bgih, u3B, 0, 0, 0);
            u3B = __builtin_amdgcn_mfma_f32_32x32x16_bf16(arh, bgil, u3B, 0, 0, 0);
        }
    }
    {
        int x2 = nh * 32 + l31;
#pragma unroll
        for (int r = 0; r < 16; ++r) {
            int z = mtA * 32 + (r & 3) + 8 * (r >> 2) + 4 * kg;
            if (z < 85) {
                float ar = u1A[r] - u2A[r];
                float ai = u3A[r];
                Ar[base + x2 * 85 + z] = ar;
                Ai[base + x2 * 85 + z] = ai;
                Apk[pkbase + ((size_t)x2 * 85 + z) * 4] = pack2(ar, ai);
            }
        }
        if (mg == 0) {
#pragma unroll
            for (int r = 0; r < 16; ++r) {
                int z = 32 + (r & 3) + 8 * (r >> 2) + 4 * kg;
                float ar = u1B[r] - u2B[r];
                float ai = u3B[r];
                Ar[base + x2 * 85 + z] = ar;
                Ai[base + x2 * 85 + z] = ai;
                Apk[pkbase + ((size_t)x2 * 85 + z) * 4] = pack2(ar, ai);
            }
        }
    }
}

// ---------------- K-wprep: pack complex conv weights into MFMA A-layout ----------------
// 3x3 convs c 0..7: [conv][tap 9][chunk 4][tile 8][16][32] (1,179,648).
// c0 l=0,1 at 1,179,648: [l][wtap 2 (hi,lo)][chunk 4][tile 8][16][32] (65,536).
__global__ __launch_bounds__(256) void k_wprep(const float* __restrict__ cA_wr,
                                               const float* __restrict__ cA_wi,
                                               const float* __restrict__ cB_wr,
                                               const float* __restrict__ cB_wi,
                                               const float* __restrict__ c0_wr,
                                               const float* __restrict__ c0_wi,
                                               short* __restrict__ wt) {
    int idx = blockIdx.x * 256 + threadIdx.x;
    if (idx >= 1245184) return;
    int c32 = idx & 31;
    int m = (idx >> 5) & 127;
    int ci_l = c32 >> 1;
    int part = c32 & 1;
    int co = m & 63;
    const float *wr, *wi;
    size_t woff;
    bool lo = false;
    int chunk;
    if (idx < 1179648) {
        chunk = (idx >> 12) & 3;
        int tap = (idx >> 14) % 9;
        int conv = idx / 147456;
        int l = conv >> 2, k1 = (conv >> 1) & 1, ab = conv & 1;
        int ci = chunk * 16 + ci_l;
        woff = (((size_t)(l * 2 + k1) * 64 + co) * 64 + ci) * 9 + tap;
        wr = ab ? cB_wr : cA_wr;
        wi = ab ? cB_wi : cA_wi;
    } else {
        int i2 = idx - 1179648;
        chunk = (i2 >> 12) & 3;
        lo = (i2 >> 14) & 1;
        int l = i2 >> 15;
        int ci = chunk * 16 + ci_l;
        woff = ((size_t)(l * 64 + co)) * 64 + ci;
        wr = c0_wr; wi = c0_wi;
    }
    float a = wr[woff], bb = wi[woff];
    float v = (m < 64) ? (part ? -bb : a) : (part ? a : bb);
    if (lo) v = v - bf2f(f2bf(v));
    wt[idx] = f2bf(v);
}

// ---------------- K7: complex 3x3 dilated conv, packed bf16, global_load_lds + dbuf ----
// LDS: [2 buf][12 rows = (xr*4+cg)][85 f][8 shorts]; lane-linear 16B slots.
// mode 0: write packed h (bias only) to out_pk; mode 1: relu+combine accumulate into yfull.
__global__ __launch_bounds__(256, 4) void k_conv3p(const int* __restrict__ in_pk,
                                                   const short* __restrict__ wt,
                                                   const float* __restrict__ b_r,
                                                   const float* __restrict__ b_i,
                                                   int K, int mode,
                                                   const float* __restrict__ l0w,
                                                   int* __restrict__ out_pk,
                                                   float* __restrict__ yfull) {
    __shared__ __align__(16) short inT[2][1020 * 8];   // 2 x 16,320 B
    int blk = blockIdx.x;
    int swz = (blk & 7) * (gridDim.x >> 3) + (blk >> 3);   // XCD-contiguous (grid%8==0)
    int b = swz >> 6, x0 = swz & 63;
    int tid = threadIdx.x;
    int lane = tid & 63, wid = tid >> 6;
    int wrow = wid & 1, wcol = wid >> 1;
    int l15 = lane & 15, g = lane >> 4;

#define STAGE(CC, BUFI)                                                       \
    do {                                                                      \
        _Pragma("unroll")                                                     \
        for (int it = 0; it < 4; ++it) {                                      \
            int idx = tid + it * 256;                                         \
            if (idx < 1020) {                                                 \
                int f = idx % 85;                                             \
                int rc = idx / 85;                                            \
                int xr = rc >> 2, cg = rc & 3;                                \
                int xg = x0 + (xr - 1) * K;                                   \
                if ((unsigned)xg < 64u) {                                     \
                    const int* src = in_pk +                                  \
                        (((size_t)((b * 16 + (CC) * 4 + cg) * 64 + xg)) * 85 + f) * 4; \
                    async16(src, &inT[BUFI][(wid * 64 + it * 256) * 8]);      \
                }                                                             \
            }                                                                 \
        }                                                                     \
    } while (0)

    // zero both buffers (OOB x-rows stay zero; valid rows fully overwritten each chunk)
    { int* p = (int*)&inT[0][0];
      for (int i = tid; i < 2 * 1020 * 4; i += 256) p[i] = 0; }
    __syncthreads();

    f32x4 acc[4][3];
#pragma unroll
    for (int a = 0; a < 4; ++a)
#pragma unroll
        for (int j = 0; j < 3; ++j) acc[a][j] = f32x4{0.f, 0.f, 0.f, 0.f};

    STAGE(0, 0);
    __syncthreads();   // drains vmcnt -> buf0 ready

    int cur = 0;
    for (int chunk = 0; chunk < 4; ++chunk) {
        if (chunk < 3) {
            if (chunk == 0) STAGE(1, 1);
            else if (chunk == 1) STAGE(2, 0);
            else STAGE(3, 1);
        }
        const short* bb = &inT[cur][0];
#pragma unroll
        for (int u = 0; u < 3; ++u) {
#pragma unroll
            for (int v = 0; v < 3; ++v) {
                int tap = u * 3 + v;
                short8v afr[4];
#pragma unroll
                for (int a = 0; a < 4; ++a) {
                    int tile = (a < 2) ? (wrow * 2 + a) : (wrow * 2 + a + 2);
                    const short* ap = wt + ((((size_t)tap * 4 + chunk) * 8 + tile) * 16 + l15) * 32 + g * 8;
                    afr[a] = *(const short8v*)ap;
                }
                short8v bfr[3];
#pragma unroll
                for (int j = 0; j < 3; ++j) {
                    int fs = (wcol * 3 + j) * 16 + l15 + (v - 1) * K;
                    bool inr = ((unsigned)fs < 85u);
                    int fsc = inr ? fs : 0;
                    short8v t8 = *(const short8v*)&bb[((u * 4 + g) * 85 + fsc) * 8];
                    bfr[j] = inr ? t8 : short8v{0, 0, 0, 0, 0, 0, 0, 0};
                }
#pragma unroll
                for (int a = 0; a < 4; ++a)
#pragma unroll
                    for (int j = 0; j < 3; ++j)
                        acc[a][j] = __builtin_amdgcn_mfma_f32_16x16x32_bf16(afr[a], bfr[j],
                                                                            acc[a][j], 0, 0, 0);
            }
        }
        __syncthreads();   // drains prefetch loads + compute's LDS reads
        cur ^= 1;
    }
#undef STAGE

    float w0 = 0.f, w1 = 0.f;
    if (mode == 1) { w0 = l0w[0]; w1 = l0w[1]; }
#pragma unroll
    for (int a = 0; a < 2; ++a) {
#pragma unroll
        for (int j = 0; j < 3; ++j) {
            int f = (wcol * 3 + j) * 16 + l15;
            if (f < NF) {
                if (mode == 0) {
                    int4 o;
#pragma unroll
                    for (int reg = 0; reg < 4; ++reg) {
                        int co = (wrow * 2 + a) * 16 + g * 4 + reg;
                        float vrq = acc[a][j][reg]     + b_r[co] - b_i[co];
                        float viq = acc[a + 2][j][reg] + b_r[co] + b_i[co];
                        ((int*)&o)[reg] = pack2(vrq, viq);
                    }
                    int co4 = (wrow * 2 + a) * 4 + g;
                    ((int4*)out_pk)[((size_t)((b * 16 + co4) * 64 + x0)) * 85 + f] = o;
                } else {
#pragma unroll
                    for (int reg = 0; reg < 4; ++reg) {
                        int co = (wrow * 2 + a) * 16 + g * 4 + reg;
                        float vrq = acc[a][j][reg]     + b_r[co] - b_i[co];
                        float viq = acc[a + 2][j][reg] + b_r[co] + b_i[co];
                        size_t o = ((size_t)(b * 64 + co) * 64 + x0) * NF + f;
                        yfull[o] += (fmaxf(vrq, 0.f) * w0 + fmaxf(viq, 0.f) * w1) * INV3;
                    }
                }
            }
        }
    }
}

// ---------------- K6: c0 1x1 complex conv via MFMA (fp32 in, 3-term hi/lo) ----------------
__global__ __launch_bounds__(256, 4) void k_c0m(const float* __restrict__ Ar,
                                                const float* __restrict__ Ai,
                                                const short* __restrict__ wt,
                                                const float* __restrict__ b_r,
                                                const float* __restrict__ b_i,
                                                const float* __restrict__ l0w,
                                                float* __restrict__ yfull) {
    __shared__ __align__(16) short inT[100 * 80];  // 16,000 B
    int blk = blockIdx.x;
    int swz = (blk & 7) * (gridDim.x >> 3) + (blk >> 3);
    int b = swz >> 6, x0 = swz & 63;
    int tid = threadIdx.x;
    int lane = tid & 63, wid = tid >> 6;
    int wrow = wid & 1, wcol = wid >> 1;
    int l15 = lane & 15, g = lane >> 4;

    f32x4 acc[4][3];
#pragma unroll
    for (int a = 0; a < 4; ++a)
#pragma unroll
        for (int j = 0; j < 3; ++j) acc[a][j] = f32x4{0.f, 0.f, 0.f, 0.f};

    for (int chunk = 0; chunk < 4; ++chunk) {
        if (chunk > 0) __syncthreads();
        for (int idx = tid; idx < 340; idx += 256) {
            int f = idx % 85;
            int cg = idx / 85;
            int4 dh, dl;
#pragma unroll
            for (int q = 0; q < 4; ++q) {
                int ci = chunk * 16 + cg * 4 + q;
                size_t s = ((size_t)(b * 64 + ci) * 64 + x0) * 85 + f;
                float vr = Ar[s], vi = Ai[s];
                ((int*)&dh)[q] = pack2(vr, vi);
                ((int*)&dl)[q] = pack2(vr - bf2f(f2bf(vr)), vi - bf2f(f2bf(vi)));
            }
            short* rowp = &inT[(f + 2) * 80];
            *(int4*)&rowp[cg * 8] = dh;
            *(int4*)&rowp[32 + cg * 8] = dl;
        }
        __syncthreads();
#pragma unroll
        for (int combo = 0; combo < 3; ++combo) {
            int wtap = (combo == 2) ? 1 : 0;
            int kkB = (combo == 1) ? 1 : 0;
            short8v afr[4];
#pragma unroll
            for (int a = 0; a < 4; ++a) {
                int tile = (a < 2) ? (wrow * 2 + a) : (wrow * 2 + a + 2);
                const short* ap = wt + ((((size_t)wtap * 4 + chunk) * 8 + tile) * 16 + l15) * 32 + g * 8;
                afr[a] = *(const short8v*)ap;
            }
            short8v bfr[3];
#pragma unroll
            for (int j = 0; j < 3; ++j) {
                int fs = (wcol * 3 + j) * 16 + l15 + 2;
                bfr[j] = *(const short8v*)&inT[fs * 80 + kkB * 32 + g * 8];
            }
#pragma unroll
            for (int a = 0; a < 4; ++a)
#pragma unroll
                for (int j = 0; j < 3; ++j)
                    acc[a][j] = __builtin_amdgcn_mfma_f32_16x16x32_bf16(afr[a], bfr[j],
                                                                        acc[a][j], 0, 0, 0);
        }
    }

    float w0 = l0w[0], w1 = l0w[1];
#pragma unroll
    for (int a = 0; a < 2; ++a) {
#pragma unroll
        for (int j = 0; j < 3; ++j) {
            int f = (wcol * 3 + j) * 16 + l15;
            if (f < NF) {
#pragma unroll
                for (int reg = 0; reg < 4; ++reg) {
                    int co = (wrow * 2 + a) * 16 + g * 4 + reg;
                    float vrq = acc[a][j][reg]     + b_r[co] - b_i[co];
                    float viq = acc[a + 2][j][reg] + b_r[co] + b_i[co];
                    size_t o = ((size_t)(b * 64 + co) * 64 + x0) * NF + f;
                    yfull[o] = (fmaxf(vrq, 0.f) * w0 + fmaxf(viq, 0.f) * w1) * INV3;
                }
            }
        }
    }
}

// ---------------- K8: mean over freq axis + l0 bias ----------------
__global__ __launch_bounds__(256) void k_reduce(const float* __restrict__ yfull,
                                                const float* __restrict__ l0b,
                                                float* __restrict__ y2, int bc) {
    int i = blockIdx.x * 256 + threadIdx.x;
    if (i >= bc * DM * NF) return;
    int f = i % NF;
    int rest = i / NF;
    int n = rest & 63;
    int b = rest >> 6;
    float s = 0.f;
    const float* p = yfull + ((size_t)(b * 64 + n) * 64) * NF + f;
    for (int x = 0; x < 64; ++x) s += p[x * NF];
    y2[i] = s * (1.f / 64.f) + l0b[0];
}

// ---------------- K9: l2 (NF->ALL) + transpose + LayerNorm ----------------
__global__ __launch_bounds__(64) void k_l2ln(const float* __restrict__ y2,
                                             const float* __restrict__ l2w,
                                             const float* __restrict__ l2b,
                                             const float* __restrict__ g,
                                             const float* __restrict__ be,
                                             float* __restrict__ enc, int b0) {
    int bl = blockIdx.x / ALLT;
    int a = blockIdx.x % ALLT;
    int d = threadIdx.x;
    const float* wp = l2w + (size_t)a * NF;
    const float* yp = y2 + (size_t)(bl * 64 + d) * NF;
    float acc = l2b[a];
    for (int f = 0; f < NF; ++f) acc += yp[f] * wp[f];
    float s = acc, s2 = acc * acc;
    for (int m = 32; m >= 1; m >>= 1) { s += __shfl_xor(s, m); s2 += __shfl_xor(s2, m); }
    float mu = s * (1.f / 64.f);
    float var = s2 * (1.f / 64.f) - mu * mu;
    float rs = rsqrtf(var + 1e-5f);
    enc[((size_t)(b0 + bl) * ALLT + a) * DM + d] = (acc - mu) * rs * g[d] + be[d];
}

// ---------------- K10: T[b,ci,j] = sum_hx enc[b,ci,2hx+j-1]*l1w[hx] ----------------
__global__ __launch_bounds__(256) void k_T(const float* __restrict__ enc,
                                           const float* __restrict__ l1w,
                                           float* __restrict__ T) {
    int i = blockIdx.x * 256 + threadIdx.x;
    if (i >= Bt * ALLT * 3) return;
    int j = i % 3;
    int rest = i / 3;
    int ci = rest % ALLT;
    int b = rest / ALLT;
    const float* e = enc + ((size_t)b * ALLT + ci) * DM;
    float s = 0.f;
    for (int hx = 0; hx < 32; ++hx) {
        int p = 2 * hx + j - 1;
        if (p >= 0 && p < DM) s += e[p] * l1w[hx];
    }
    T[i] = s;
}

// ---------------- K11: seq_series[b,co] ----------------
__global__ __launch_bounds__(256) void k_seq(const float* __restrict__ T,
                                             const float* __restrict__ cvw,
                                             const float* __restrict__ cvb,
                                             const float* __restrict__ l1w,
                                             const float* __restrict__ l1b,
                                             float* __restrict__ out) {
    int i = blockIdx.x * 256 + threadIdx.x;
    if (i >= Bt * ALLT) return;
    int co = i % ALLT;
    int b = i / ALLT;
    float sl1 = 0.f;
    for (int hx = 0; hx < 32; ++hx) sl1 += l1w[hx];
    const float* tp = T + (size_t)b * ALLT * 3;
    const float* wp = cvw + (size_t)co * ALLT * 3;
    float s = 0.f;
    for (int q = 0; q < ALLT * 3; ++q) s += tp[q] * wp[q];
    out[i] = s + cvb[co] * sl1 + l1b[0];
}

// ---------------- K12: projection + denorm, last PRED steps ----------------
__global__ __launch_bounds__(256) void k_dec(const float* __restrict__ enc,
                                             const float* __restrict__ pw,
                                             const float* __restrict__ pb,
                                             const float* __restrict__ mean,
                                             const float* __restrict__ stdv,
                                             float* __restrict__ out) {
    int i = blockIdx.x * 256 + threadIdx.x;
    if (i >= Bt * PRED * CIN) return;
    int c = i % CIN;
    int rest = i / CIN;
    int tt = rest % PRED;
    int b = rest / PRED;
    const float* e = enc + ((size_t)b * ALLT + SEQ + tt) * DM;
    const float* w = pw + c * DM;
    float s = pb[c];
    for (int d = 0; d < DM; ++d) s += e[d] * w[d];
    out[i] = s * stdv[b * CIN + c] + mean[b * CIN + c];
}

extern "C" void kernel_launch(void* const* d_in, const int* in_sizes, int n_in,
                              void* d_out, int out_size, void* d_ws, size_t ws_size,
                              hipStream_t stream) {
    (void)in_sizes; (void)n_in; (void)out_size;
    const float* x_enc  = (const float*)d_in[0];
    const float* x_mark = (const float*)d_in[1];
    const float* tok_w  = (const float*)d_in[4];
    const float* temp_w = (const float*)d_in[5];
    const float* pl_w   = (const float*)d_in[6];
    const float* pl_b   = (const float*)d_in[7];
    const float* ln_g   = (const float*)d_in[8];
    const float* ln_b   = (const float*)d_in[9];
    const float* c0_wr  = (const float*)d_in[10];
    const float* c0_wi  = (const float*)d_in[11];
    const float* c0_br  = (const float*)d_in[12];
    const float* c0_bi  = (const float*)d_in[13];
    const float* cA_wr  = (const float*)d_in[14];
    const float* cA_wi  = (const float*)d_in[15];
    const float* cA_br  = (const float*)d_in[16];
    const float* cA_bi  = (const float*)d_in[17];
    const float* cB_wr  = (const float*)d_in[18];
    const float* cB_wi  = (const float*)d_in[19];
    const float* cB_br  = (const float*)d_in[20];
    const float* cB_bi  = (const float*)d_in[21];
    const float* l0_w   = (const float*)d_in[22];
    const float* l0_b   = (const float*)d_in[23];
    const float* l2_w   = (const float*)d_in[24];
    const float* l2_b   = (const float*)d_in[25];
    const float* cv_w   = (const float*)d_in[26];
    const float* cv_b   = (const float*)d_in[27];
    const float* l1_w   = (const float*)d_in[28];
    const float* l1_b   = (const float*)d_in[29];
    const float* proj_w = (const float*)d_in[30];
    const float* proj_b = (const float*)d_in[31];

    float* out0 = (float*)d_out;                    // dec: [32,336,7]
    float* out1 = out0 + (size_t)Bt * PRED * CIN;   // seq_series: [32,672]

    float* ws = (float*)d_ws;
    size_t off = 0;
    float* enc  = ws + off; off += (size_t)Bt * ALLT * DM;
    float* enc0 = ws + off; off += (size_t)Bt * SEQ * DM;
    float* mean = ws + off; off += 256;
    float* stdv = ws + off; off += 256;
    short* wtbuf = (short*)(ws + off); off += 622592;   // 1,245,184 bf16 packed weights

    const size_t perb = (size_t)DM * NFFT * NF;  // 348,160
    int Bc = 32;
    while (Bc > 1) {
        size_t need = (off + (size_t)Bc * DM * NF + 6 * (size_t)Bc * perb) * sizeof(float);
        if (need <= ws_size) break;
        Bc >>= 1;
    }
    float* y2 = ws + off; off += (size_t)Bc * DM * NF;
    float* Sr = ws + off; off += (size_t)Bc * perb;
    float* Si = ws + off; off += (size_t)Bc * perb;
    float* Ar = ws + off; off += (size_t)Bc * perb;
    float* Ai = ws + off; off += (size_t)Bc * perb;
    float* yfull = ws + off; off += (size_t)Bc * perb;
    int*   Apk = (int*)(ws + off); off += (size_t)Bc * perb;
    int*   Hpk = (int*)Sr;   // reuse: S dead after k_qka_m
    float* Tb = enc0;

    k_stats<<<Bt * CIN, 64, 0, stream>>>(x_enc, mean, stdv);
    k_wprep<<<(1245184 + 255) / 256, 256, 0, stream>>>(cA_wr, cA_wi, cB_wr, cB_wi,
                                                       c0_wr, c0_wi, wtbuf);
    k_embed<<<(Bt * SEQ * DM + 255) / 256, 256, 0, stream>>>(x_enc, x_mark, tok_w, temp_w,
                                                             mean, stdv, enc0);
    k_plin2<<<Bt * 14, 256, 0, stream>>>(enc0, pl_w, pl_b, enc);

    for (int l = 0; l < 2; ++l) {
        for (int b0 = 0; b0 < Bt; b0 += Bc) {
            k_stft<<<Bc * 64, 256, 0, stream>>>(enc, b0, Sr, Si);
            k_qka_m<<<Bc * 64, 256, 0, stream>>>(Sr, Si, Ar, Ai, Apk);
            k_c0m<<<Bc * 64, 256, 0, stream>>>(Ar, Ai, wtbuf + 1179648 + (size_t)l * 32768,
                                               c0_br + l * 64, c0_bi + l * 64,
                                               l0_w + l * 2, yfull);
            for (int k = 1; k <= 2; ++k) {
                int convA = l * 4 + (k - 1) * 2;
                size_t boff = ((size_t)l * 2 + (k - 1)) * 64;
                k_conv3p<<<Bc * 64, 256, 0, stream>>>(Apk, wtbuf + (size_t)convA * 147456,
                                                      cA_br + boff, cA_bi + boff, k, 0,
                                                      l0_w + l * 2, Hpk, yfull);
                k_conv3p<<<Bc * 64, 256, 0, stream>>>(Hpk, wtbuf + (size_t)(convA + 1) * 147456,
                                                      cB_br + boff, cB_bi + boff, k, 1,
                                                      l0_w + l * 2, Hpk, yfull);
            }
            k_reduce<<<(Bc * DM * NF + 255) / 256, 256, 0, stream>>>(yfull, l0_b + l, y2, Bc);
            k_l2ln<<<Bc * ALLT, 64, 0, stream>>>(y2, l2_w + (size_t)l * ALLT * NF,
                                                 l2_b + (size_t)l * ALLT, ln_g, ln_b, enc, b0);
        }
    }

    k_T<<<(Bt * ALLT * 3 + 255) / 256, 256, 0, stream>>>(enc, l1_w, Tb);
    k_seq<<<(Bt * ALLT + 255) / 256, 256, 0, stream>>>(Tb, cv_w, cv_b, l1_w, l1_b, out1);
    k_dec<<<(Bt * PRED * CIN + 255) / 256, 256, 0, stream>>>(enc, proj_w, proj_b, mean, stdv, out0);
}

// Round 9
// 1474.219 us; speedup vs baseline: 1.2037x; 1.2037x over previous
//
#include <hip/hip_runtime.h>

typedef __attribute__((ext_vector_type(8))) short short8v;
typedef __attribute__((ext_vector_type(4))) float f32x4;
typedef __attribute__((ext_vector_type(16))) float f32x16;

static constexpr int Bt = 32;
static constexpr int SEQ = 336, PRED = 336, CIN = 7, ALLT = 672;
static constexpr int DM = 64, NFFT = 64, HOP = 8, NF = 85;
static constexpr int MARK = 4;
static constexpr float INV3 = 1.0f / 3.0f;

__device__ inline short f2bf(float v) {
    unsigned u = __float_as_uint(v);
    u += 0x7fffu + ((u >> 16) & 1u);   // round-to-nearest-even
    return (short)(u >> 16);
}
__device__ inline float bf2f(short h) {
    return __uint_as_float(((unsigned)(unsigned short)h) << 16);
}
__device__ inline int pack2(float r, float i) {
    return ((int)(unsigned short)f2bf(r)) | (((int)(unsigned short)f2bf(i)) << 16);
}
__device__ inline void async16(const int* g, short* l) {
    __builtin_amdgcn_global_load_lds(
        (const __attribute__((address_space(1))) unsigned int*)g,
        (__attribute__((address_space(3))) unsigned int*)l, 16, 0, 0);
}

// ---------------- K1: per (b,c) mean / std over time ----------------
__global__ __launch_bounds__(64) void k_stats(const float* __restrict__ x,
                                              float* __restrict__ mean,
                                              float* __restrict__ stdv) {
    int bc = blockIdx.x;              // b*7+c
    int b = bc / CIN, c = bc % CIN;
    int lane = threadIdx.x;
    float s = 0.f, s2 = 0.f;
    for (int t = lane; t < SEQ; t += 64) {
        float v = x[(b * SEQ + t) * CIN + c];
        s += v; s2 += v * v;
    }
    for (int m = 32; m >= 1; m >>= 1) { s += __shfl_xor(s, m); s2 += __shfl_xor(s2, m); }
    if (lane == 0) {
        float mu = s / SEQ;
        float var = s2 / SEQ - mu * mu;
        mean[bc] = mu;
        stdv[bc] = sqrtf(var + 1e-5f);
    }
}

// ---------------- K2: embedding (token conv + temporal + PE) ----------------
__global__ __launch_bounds__(256) void k_embed(const float* __restrict__ x,
                                               const float* __restrict__ mark,
                                               const float* __restrict__ tok_w,
                                               const float* __restrict__ temp_w,
                                               const float* __restrict__ mean,
                                               const float* __restrict__ stdv,
                                               float* __restrict__ enc0) {
    int i = blockIdx.x * 256 + threadIdx.x;
    if (i >= Bt * SEQ * DM) return;
    int d = i & 63;
    int t = (i >> 6) % SEQ;
    int b = i / (SEQ * DM);
    float val = 0.f;
    for (int c = 0; c < CIN; ++c) {
        float mu = mean[b * CIN + c];
        float is = 1.f / stdv[b * CIN + c];
        for (int j = 0; j < 3; ++j) {
            int tt = t + j - 1;
            if (tt < 0) tt += SEQ;
            if (tt >= SEQ) tt -= SEQ;
            float xv = (x[(b * SEQ + tt) * CIN + c] - mu) * is;
            val += xv * tok_w[(d * CIN + c) * 3 + j];
        }
    }
    float mk = 0.f;
    for (int m = 0; m < MARK; ++m) mk += mark[(b * SEQ + t) * MARK + m] * temp_w[d * MARK + m];
    float div = expf(-(float)(d & ~1) * (9.210340371976184f / (float)DM));
    float arg = (float)t * div;
    float pe = (d & 1) ? cosf(arg) : sinf(arg);
    enc0[i] = val + mk + pe;
}

// ---------------- K3: predict_linear (time 336 -> 672), LDS-blocked ----------------
__global__ __launch_bounds__(256) void k_plin2(const float* __restrict__ enc0,
                                               const float* __restrict__ pl_w,
                                               const float* __restrict__ pl_b,
                                               float* __restrict__ enc) {
    __shared__ float Et[56 * 64];     // [t][d]
    __shared__ float Wt[56 * 49];     // [t][a], pad 49
    int blk = blockIdx.x;
    int b = blk / 14, at = blk % 14;
    int abase = at * 48;
    int tid = threadIdx.x;
    int a0 = (tid & 15) * 3;
    int d0 = (tid >> 4) * 4;
    float acc[3][4];
#pragma unroll
    for (int q = 0; q < 3; ++q)
#pragma unroll
        for (int r = 0; r < 4; ++r) acc[q][r] = 0.f;
    for (int tc = 0; tc < 6; ++tc) {
        if (tc) __syncthreads();
        for (int i = tid; i < 56 * 64; i += 256)
            Et[i] = enc0[((size_t)b * SEQ + tc * 56) * DM + i];
        for (int i = tid; i < 48 * 56; i += 256) {
            int r = i / 56, c = i - r * 56;
            Wt[c * 49 + r] = pl_w[(size_t)(abase + r) * SEQ + tc * 56 + c];
        }
        __syncthreads();
#pragma unroll 4
        for (int t = 0; t < 56; ++t) {
            float4 e = *(const float4*)&Et[t * 64 + d0];
            float w0 = Wt[t * 49 + a0];
            float w1 = Wt[t * 49 + a0 + 1];
            float w2 = Wt[t * 49 + a0 + 2];
            acc[0][0] += w0 * e.x; acc[0][1] += w0 * e.y;
            acc[0][2] += w0 * e.z; acc[0][3] += w0 * e.w;
            acc[1][0] += w1 * e.x; acc[1][1] += w1 * e.y;
            acc[1][2] += w1 * e.z; acc[1][3] += w1 * e.w;
            acc[2][0] += w2 * e.x; acc[2][1] += w2 * e.y;
            acc[2][2] += w2 * e.z; acc[2][3] += w2 * e.w;
        }
    }
#pragma unroll
    for (int q = 0; q < 3; ++q) {
        int a = abase + a0 + q;
        float bias = pl_b[a];
        float4 o = {acc[q][0] + bias, acc[q][1] + bias, acc[q][2] + bias, acc[q][3] + bias};
        *(float4*)&enc[((size_t)b * ALLT + a) * DM + d0] = o;
    }
}

// ---------------- K4+K5 fused: STFT (MFMA DFT) + qk + sigmoid + a = gS ----------------
// One block per (bl, n). Outputs packed bf16 hi/lo a into Apk/Apl.
__global__ __launch_bounds__(256) void k_stqka(const float* __restrict__ enc, int b0,
                                               int* __restrict__ Apk,
                                               int* __restrict__ Apl) {
    __shared__ __align__(16) short L[54272];   // 108,544 B, two overlaid regions
    // region A (staging for DFT)
    constexpr int TCH = 0, TCL = 4608, TSH = 9216, TSL = 13824;   // twiddle [64][72]
    constexpr int XWH = 18432, XWL = 25344;                       // frames  [96][72]
    float* xp  = (float*)&L[32256];   // [736]
    float* twc = (float*)&L[33728];   // [64]
    float* tws = (float*)&L[33984];   // [64]
    // region B (compute) — overlays region A after DFT
    constexpr int SRH = 0, SIH = 6656, SRL = 13312, SIL = 19968;        // rows [64][104]
    constexpr int STRH = 26624, STRL = 33536, STIH = 40448, STIL = 47360;  // ST [96][72]
    constexpr int GRH = 0, GRL = 4608, GIH = 9216, GIL = 13824;         // g [64][72] overlay

    int bn = blockIdx.x;
    int bl = bn >> 6, n = bn & 63;
    int bg = b0 + bl;
    int tid = threadIdx.x;
    int lane = tid & 63, w = tid >> 6;
    int l31 = lane & 31, kg = lane >> 5;

    // --- 1) reflect-padded series + base twiddle tables ---
    for (int i = tid; i < ALLT + NFFT; i += 256) {
        int j = i - 32;
        if (j < 0) j = -j;
        if (j > ALLT - 1) j = 2 * (ALLT - 1) - j;
        xp[i] = enc[((size_t)bg * ALLT + j) * DM + n];
    }
    if (tid < 64) {
        float ang = (6.283185307179586f / 64.f) * (float)tid;
        twc[tid] = cosf(ang);
        tws[tid] = sinf(ang);
    }
    __syncthreads();
    // --- 2) twiddle matrices W[k][tt] split hi/lo ---
    for (int i = tid; i < 64 * 64; i += 256) {
        int k = i >> 6, tt = i & 63;
        int m = (k * tt) & 63;
        float c = twc[m], s = tws[m];
        short ch = f2bf(c); short cl = f2bf(c - bf2f(ch));
        short sh = f2bf(s); short sl = f2bf(s - bf2f(sh));
        int o = k * 72 + tt;
        L[TCH + o] = ch; L[TCL + o] = cl; L[TSH + o] = sh; L[TSL + o] = sl;
    }
    // --- 3) windowed frames xw[f][tt] split hi/lo (f>=85 zero) ---
    for (int i = tid; i < 96 * 64; i += 256) {
        int f = i >> 6, tt = i & 63;
        float v = 0.f;
        if (f < 85) v = xp[f * HOP + tt] * (0.5f - 0.5f * twc[tt]) * 0.125f;
        short vh = f2bf(v); short vl = f2bf(v - bf2f(vh));
        int o = f * 72 + tt;
        L[XWH + o] = vh; L[XWL + o] = vl;
    }
    __syncthreads();

    // --- 4) DFT via split-bf16 MFMA: S[k][f] = sum_tt W[k][tt]*xw[f][tt] ---
    int kt = w & 1;
    int ftA = (w < 2) ? 0 : 2;
    f32x16 srA, siA, srB, siB;
#pragma unroll
    for (int r = 0; r < 16; ++r) { srA[r] = 0.f; siA[r] = 0.f; srB[r] = 0.f; siB[r] = 0.f; }
#pragma unroll
    for (int tts = 0; tts < 4; ++tts) {
        int ko = (kt * 32 + l31) * 72 + tts * 16 + kg * 8;
        short8v ach = *(const short8v*)&L[TCH + ko];
        short8v acl = *(const short8v*)&L[TCL + ko];
        short8v ash = *(const short8v*)&L[TSH + ko];
        short8v asl = *(const short8v*)&L[TSL + ko];
        {
            int bo = (ftA * 32 + l31) * 72 + tts * 16 + kg * 8;
            short8v bh = *(const short8v*)&L[XWH + bo];
            short8v bl_ = *(const short8v*)&L[XWL + bo];
            srA = __builtin_amdgcn_mfma_f32_32x32x16_bf16(ach, bh, srA, 0, 0, 0);
            srA = __builtin_amdgcn_mfma_f32_32x32x16_bf16(acl, bh, srA, 0, 0, 0);
            srA = __builtin_amdgcn_mfma_f32_32x32x16_bf16(ach, bl_, srA, 0, 0, 0);
            siA = __builtin_amdgcn_mfma_f32_32x32x16_bf16(ash, bh, siA, 0, 0, 0);
            siA = __builtin_amdgcn_mfma_f32_32x32x16_bf16(asl, bh, siA, 0, 0, 0);
            siA = __builtin_amdgcn_mfma_f32_32x32x16_bf16(ash, bl_, siA, 0, 0, 0);
        }
        if (w < 2) {
            int bo = (32 + l31) * 72 + tts * 16 + kg * 8;   // ft = 1
            short8v bh = *(const short8v*)&L[XWH + bo];
            short8v bl_ = *(const short8v*)&L[XWL + bo];
            srB = __builtin_amdgcn_mfma_f32_32x32x16_bf16(ach, bh, srB, 0, 0, 0);
            srB = __builtin_amdgcn_mfma_f32_32x32x16_bf16(acl, bh, srB, 0, 0, 0);
            srB = __builtin_amdgcn_mfma_f32_32x32x16_bf16(ach, bl_, srB, 0, 0, 0);
            siB = __builtin_amdgcn_mfma_f32_32x32x16_bf16(ash, bh, siB, 0, 0, 0);
            siB = __builtin_amdgcn_mfma_f32_32x32x16_bf16(asl, bh, siB, 0, 0, 0);
            siB = __builtin_amdgcn_mfma_f32_32x32x16_bf16(ash, bl_, siB, 0, 0, 0);
        }
    }
    __syncthreads();   // region A dead; write region B

    // --- 5) write S into row-major + transposed split arrays from registers ---
    {
        int fA = ftA * 32 + l31;
#pragma unroll
        for (int r = 0; r < 16; ++r) {
            int k = kt * 32 + (r & 3) + 8 * (r >> 2) + 4 * kg;
            float sv = srA[r], iv = -siA[r];
            short rh = f2bf(sv); short rl = f2bf(sv - bf2f(rh));
            short ih = f2bf(iv); short il = f2bf(iv - bf2f(ih));
            L[SRH + k * 104 + fA] = rh; L[SRL + k * 104 + fA] = rl;
            L[SIH + k * 104 + fA] = ih; L[SIL + k * 104 + fA] = il;
            L[STRH + fA * 72 + k] = rh; L[STRL + fA * 72 + k] = rl;
            L[STIH + fA * 72 + k] = ih; L[STIL + fA * 72 + k] = il;
        }
        if (w < 2) {
            int fB = 32 + l31;
#pragma unroll
            for (int r = 0; r < 16; ++r) {
                int k = kt * 32 + (r & 3) + 8 * (r >> 2) + 4 * kg;
                float sv = srB[r], iv = -siB[r];
                short rh = f2bf(sv); short rl = f2bf(sv - bf2f(rh));
                short ih = f2bf(iv); short il = f2bf(iv - bf2f(ih));
                L[SRH + k * 104 + fB] = rh; L[SRL + k * 104 + fB] = rl;
                L[SIH + k * 104 + fB] = ih; L[SIL + k * 104 + fB] = il;
                L[STRH + fB * 72 + k] = rh; L[STRL + fB * 72 + k] = rl;
                L[STIH + fB * 72 + k] = ih; L[STIL + fB * 72 + k] = il;
            }
        }
    }
    __syncthreads();

    // --- 6) phase 1: qk (split-bf16, 3-term) ---
    int mh = w >> 1, nh = w & 1;
    f32x16 P, Q, R;
#pragma unroll
    for (int r = 0; r < 16; ++r) { P[r] = 0.f; Q[r] = 0.f; R[r] = 0.f; }
#pragma unroll
    for (int f0 = 0; f0 < 96; f0 += 16) {
        int ka = f0 + kg * 8;
        int ra = (mh * 32 + l31) * 104 + ka;
        int rb = (nh * 32 + l31) * 104 + ka;
        short8v a_rh = *(const short8v*)&L[SRH + ra];
        short8v a_rl = *(const short8v*)&L[SRL + ra];
        short8v a_ih = *(const short8v*)&L[SIH + ra];
        short8v a_il = *(const short8v*)&L[SIL + ra];
        short8v b_rh = *(const short8v*)&L[SRH + rb];
        short8v b_rl = *(const short8v*)&L[SRL + rb];
        short8v b_ih = *(const short8v*)&L[SIH + rb];
        short8v b_il = *(const short8v*)&L[SIL + rb];
        P = __builtin_amdgcn_mfma_f32_32x32x16_bf16(a_rh, b_rh, P, 0, 0, 0);
        P = __builtin_amdgcn_mfma_f32_32x32x16_bf16(a_rl, b_rh, P, 0, 0, 0);
        P = __builtin_amdgcn_mfma_f32_32x32x16_bf16(a_rh, b_rl, P, 0, 0, 0);
        Q = __builtin_amdgcn_mfma_f32_32x32x16_bf16(a_ih, b_ih, Q, 0, 0, 0);
        Q = __builtin_amdgcn_mfma_f32_32x32x16_bf16(a_il, b_ih, Q, 0, 0, 0);
        Q = __builtin_amdgcn_mfma_f32_32x32x16_bf16(a_ih, b_il, Q, 0, 0, 0);
        R = __builtin_amdgcn_mfma_f32_32x32x16_bf16(a_rh, b_ih, R, 0, 0, 0);
        R = __builtin_amdgcn_mfma_f32_32x32x16_bf16(a_rl, b_ih, R, 0, 0, 0);
        R = __builtin_amdgcn_mfma_f32_32x32x16_bf16(a_rh, b_il, R, 0, 0, 0);
        R = __builtin_amdgcn_mfma_f32_32x32x16_bf16(a_ih, b_rh, R, 0, 0, 0);
        R = __builtin_amdgcn_mfma_f32_32x32x16_bf16(a_il, b_rh, R, 0, 0, 0);
        R = __builtin_amdgcn_mfma_f32_32x32x16_bf16(a_ih, b_rl, R, 0, 0, 0);
    }
    __syncthreads();   // row arrays dead; g overlays them

    {
        int y = nh * 32 + l31;
#pragma unroll
        for (int r = 0; r < 16; ++r) {
            int x = mh * 32 + (r & 3) + 8 * (r >> 2) + 4 * kg;
            float gr = 1.f / (1.f + __expf(-(P[r] - Q[r])));
            float gi = 1.f / (1.f + __expf(-R[r]));
            short gh = f2bf(gr); short gl = f2bf(gr - bf2f(gh));
            short jh = f2bf(gi); short jl = f2bf(gi - bf2f(jh));
            L[GRH + x * 72 + y] = gh; L[GRL + x * 72 + y] = gl;
            L[GIH + x * 72 + y] = jh; L[GIL + x * 72 + y] = jl;
        }
    }
    __syncthreads();

    // --- 7) phase 2: a^T[z,x] = sum_y S[y,z] g[x,y] (complex, full split) ---
    int mg = w >> 1;
    int mtA = (mg == 0) ? 0 : 2;
    f32x16 u1A, u2A, u3A, u1B, u2B, u3B;
#pragma unroll
    for (int r = 0; r < 16; ++r) {
        u1A[r] = 0.f; u2A[r] = 0.f; u3A[r] = 0.f;
        u1B[r] = 0.f; u2B[r] = 0.f; u3B[r] = 0.f;
    }
#pragma unroll
    for (int y0 = 0; y0 < 64; y0 += 16) {
        int kb = y0 + kg * 8;
        int gb = (nh * 32 + l31) * 72 + kb;
        short8v bgrh = *(const short8v*)&L[GRH + gb];
        short8v bgrl = *(const short8v*)&L[GRL + gb];
        short8v bgih = *(const short8v*)&L[GIH + gb];
        short8v bgil = *(const short8v*)&L[GIL + gb];
        {
            int sa = (mtA * 32 + l31) * 72 + kb;
            short8v arh = *(const short8v*)&L[STRH + sa];
            short8v arl = *(const short8v*)&L[STRL + sa];
            short8v aih = *(const short8v*)&L[STIH + sa];
            short8v ail = *(const short8v*)&L[STIL + sa];
            u1A = __builtin_amdgcn_mfma_f32_32x32x16_bf16(arh, bgrh, u1A, 0, 0, 0);
            u1A = __builtin_amdgcn_mfma_f32_32x32x16_bf16(arl, bgrh, u1A, 0, 0, 0);
            u1A = __builtin_amdgcn_mfma_f32_32x32x16_bf16(arh, bgrl, u1A, 0, 0, 0);
            u2A = __builtin_amdgcn_mfma_f32_32x32x16_bf16(aih, bgih, u2A, 0, 0, 0);
            u2A = __builtin_amdgcn_mfma_f32_32x32x16_bf16(ail, bgih, u2A, 0, 0, 0);
            u2A = __builtin_amdgcn_mfma_f32_32x32x16_bf16(aih, bgil, u2A, 0, 0, 0);
            u3A = __builtin_amdgcn_mfma_f32_32x32x16_bf16(aih, bgrh, u3A, 0, 0, 0);
            u3A = __builtin_amdgcn_mfma_f32_32x32x16_bf16(ail, bgrh, u3A, 0, 0, 0);
            u3A = __builtin_amdgcn_mfma_f32_32x32x16_bf16(aih, bgrl, u3A, 0, 0, 0);
            u3A = __builtin_amdgcn_mfma_f32_32x32x16_bf16(arh, bgih, u3A, 0, 0, 0);
            u3A = __builtin_amdgcn_mfma_f32_32x32x16_bf16(arl, bgih, u3A, 0, 0, 0);
            u3A = __builtin_amdgcn_mfma_f32_32x32x16_bf16(arh, bgil, u3A, 0, 0, 0);
        }
        if (mg == 0) {
            int sa = (1 * 32 + l31) * 72 + kb;
            short8v arh = *(const short8v*)&L[STRH + sa];
            short8v arl = *(const short8v*)&L[STRL + sa];
            short8v aih = *(const short8v*)&L[STIH + sa];
            short8v ail = *(const short8v*)&L[STIL + sa];
            u1B = __builtin_amdgcn_mfma_f32_32x32x16_bf16(arh, bgrh, u1B, 0, 0, 0);
            u1B = __builtin_amdgcn_mfma_f32_32x32x16_bf16(arl, bgrh, u1B, 0, 0, 0);
            u1B = __builtin_amdgcn_mfma_f32_32x32x16_bf16(arh, bgrl, u1B, 0, 0, 0);
            u2B = __builtin_amdgcn_mfma_f32_32x32x16_bf16(aih, bgih, u2B, 0, 0, 0);
            u2B = __builtin_amdgcn_mfma_f32_32x32x16_bf16(ail, bgih, u2B, 0, 0, 0);
            u2B = __builtin_amdgcn_mfma_f32_32x32x16_bf16(aih, bgil, u2B, 0, 0, 0);
            u3B = __builtin_amdgcn_mfma_f32_32x32x16_bf16(aih, bgrh, u3B, 0, 0, 0);
            u3B = __builtin_amdgcn_mfma_f32_32x32x16_bf16(ail, bgrh, u3B, 0, 0, 0);
            u3B = __builtin_amdgcn_mfma_f32_32x32x16_bf16(aih, bgrl, u3B, 0, 0, 0);
            u3B = __builtin_amdgcn_mfma_f32_32x32x16_bf16(arh, bgih, u3B, 0, 0, 0);
            u3B = __builtin_amdgcn_mfma_f32_32x32x16_bf16(arl, bgih, u3B, 0, 0, 0);
            u3B = __builtin_amdgcn_mfma_f32_32x32x16_bf16(arh, bgil, u3B, 0, 0, 0);
        }
    }
    // --- 8) store packed hi/lo a ---
    {
        size_t pkbase = ((size_t)(bl * 16 + (n >> 2)) * 64) * 85 * 4 + (n & 3);
        int x2 = nh * 32 + l31;
#pragma unroll
        for (int r = 0; r < 16; ++r) {
            int z = mtA * 32 + (r & 3) + 8 * (r >> 2) + 4 * kg;
            if (z < 85) {
                float ar = u1A[r] - u2A[r];
                float ai = u3A[r];
                size_t o = pkbase + ((size_t)x2 * 85 + z) * 4;
                short arh = f2bf(ar); short aih = f2bf(ai);
                Apk[o] = ((int)(unsigned short)arh) | (((int)(unsigned short)aih) << 16);
                Apl[o] = pack2(ar - bf2f(arh), ai - bf2f(aih));
            }
        }
        if (mg == 0) {
#pragma unroll
            for (int r = 0; r < 16; ++r) {
                int z = 32 + (r & 3) + 8 * (r >> 2) + 4 * kg;
                float ar = u1B[r] - u2B[r];
                float ai = u3B[r];
                size_t o = pkbase + ((size_t)x2 * 85 + z) * 4;
                short arh = f2bf(ar); short aih = f2bf(ai);
                Apk[o] = ((int)(unsigned short)arh) | (((int)(unsigned short)aih) << 16);
                Apl[o] = pack2(ar - bf2f(arh), ai - bf2f(aih));
            }
        }
    }
}

// ---------------- K-wprep: pack complex conv weights into MFMA A-layout ----------------
// 3x3 convs c 0..7: [conv][tap 9][chunk 4][tile 8][16][32] (1,179,648).
// c0 l=0,1 at 1,179,648: [l][wtap 2 (hi,lo)][chunk 4][tile 8][16][32] (65,536).
__global__ __launch_bounds__(256) void k_wprep(const float* __restrict__ cA_wr,
                                               const float* __restrict__ cA_wi,
                                               const float* __restrict__ cB_wr,
                                               const float* __restrict__ cB_wi,
                                               const float* __restrict__ c0_wr,
                                               const float* __restrict__ c0_wi,
                                               short* __restrict__ wt) {
    int idx = blockIdx.x * 256 + threadIdx.x;
    if (idx >= 1245184) return;
    int c32 = idx & 31;
    int m = (idx >> 5) & 127;
    int ci_l = c32 >> 1;
    int part = c32 & 1;
    int co = m & 63;
    const float *wr, *wi;
    size_t woff;
    bool lo = false;
    int chunk;
    if (idx < 1179648) {
        chunk = (idx >> 12) & 3;
        int tap = (idx >> 14) % 9;
        int conv = idx / 147456;
        int l = conv >> 2, k1 = (conv >> 1) & 1, ab = conv & 1;
        int ci = chunk * 16 + ci_l;
        woff = (((size_t)(l * 2 + k1) * 64 + co) * 64 + ci) * 9 + tap;
        wr = ab ? cB_wr : cA_wr;
        wi = ab ? cB_wi : cA_wi;
    } else {
        int i2 = idx - 1179648;
        chunk = (i2 >> 12) & 3;
        lo = (i2 >> 14) & 1;
        int l = i2 >> 15;
        int ci = chunk * 16 + ci_l;
        woff = ((size_t)(l * 64 + co)) * 64 + ci;
        wr = c0_wr; wi = c0_wi;
    }
    float a = wr[woff], bb = wi[woff];
    float v = (m < 64) ? (part ? -bb : a) : (part ? a : bb);
    if (lo) v = v - bf2f(f2bf(v));
    wt[idx] = f2bf(v);
}

// ---------------- K7: complex 3x3 dilated conv, packed bf16, global_load_lds + dbuf ----
__global__ __launch_bounds__(256, 4) void k_conv3p(const int* __restrict__ in_pk,
                                                   const short* __restrict__ wt,
                                                   const float* __restrict__ b_r,
                                                   const float* __restrict__ b_i,
                                                   int K, int mode,
                                                   const float* __restrict__ l0w,
                                                   int* __restrict__ out_pk,
                                                   float* __restrict__ yfull) {
    __shared__ __align__(16) short inT[2][1020 * 8];   // 2 x 16,320 B
    int blk = blockIdx.x;
    int swz = (blk & 7) * (gridDim.x >> 3) + (blk >> 3);   // XCD-contiguous (grid%8==0)
    int b = swz >> 6, x0 = swz & 63;
    int tid = threadIdx.x;
    int lane = tid & 63, wid = tid >> 6;
    int wrow = wid & 1, wcol = wid >> 1;
    int l15 = lane & 15, g = lane >> 4;

#define STAGE(CC, BUFI)                                                       \
    do {                                                                      \
        _Pragma("unroll")                                                     \
        for (int it = 0; it < 4; ++it) {                                      \
            int idx = tid + it * 256;                                         \
            if (idx < 1020) {                                                 \
                int f = idx % 85;                                             \
                int rc = idx / 85;                                            \
                int xr = rc >> 2, cg = rc & 3;                                \
                int xg = x0 + (xr - 1) * K;                                   \
                if ((unsigned)xg < 64u) {                                     \
                    const int* src = in_pk +                                  \
                        (((size_t)((b * 16 + (CC) * 4 + cg) * 64 + xg)) * 85 + f) * 4; \
                    async16(src, &inT[BUFI][(wid * 64 + it * 256) * 8]);      \
                }                                                             \
            }                                                                 \
        }                                                                     \
    } while (0)

    { int* p = (int*)&inT[0][0];
      for (int i = tid; i < 2 * 1020 * 4; i += 256) p[i] = 0; }
    __syncthreads();

    f32x4 acc[4][3];
#pragma unroll
    for (int a = 0; a < 4; ++a)
#pragma unroll
        for (int j = 0; j < 3; ++j) acc[a][j] = f32x4{0.f, 0.f, 0.f, 0.f};

    STAGE(0, 0);
    __syncthreads();

    int cur = 0;
    for (int chunk = 0; chunk < 4; ++chunk) {
        if (chunk == 0) STAGE(1, 1);
        else if (chunk == 1) STAGE(2, 0);
        else if (chunk == 2) STAGE(3, 1);
        const short* bb = &inT[cur][0];
#pragma unroll
        for (int u = 0; u < 3; ++u) {
#pragma unroll
            for (int v = 0; v < 3; ++v) {
                int tap = u * 3 + v;
                short8v afr[4];
#pragma unroll
                for (int a = 0; a < 4; ++a) {
                    int tile = (a < 2) ? (wrow * 2 + a) : (wrow * 2 + a + 2);
                    const short* ap = wt + ((((size_t)tap * 4 + chunk) * 8 + tile) * 16 + l15) * 32 + g * 8;
                    afr[a] = *(const short8v*)ap;
                }
                short8v bfr[3];
#pragma unroll
                for (int j = 0; j < 3; ++j) {
                    int fs = (wcol * 3 + j) * 16 + l15 + (v - 1) * K;
                    bool inr = ((unsigned)fs < 85u);
                    int fsc = inr ? fs : 0;
                    short8v t8 = *(const short8v*)&bb[((u * 4 + g) * 85 + fsc) * 8];
                    bfr[j] = inr ? t8 : short8v{0, 0, 0, 0, 0, 0, 0, 0};
                }
#pragma unroll
                for (int a = 0; a < 4; ++a)
#pragma unroll
                    for (int j = 0; j < 3; ++j)
                        acc[a][j] = __builtin_amdgcn_mfma_f32_16x16x32_bf16(afr[a], bfr[j],
                                                                            acc[a][j], 0, 0, 0);
            }
        }
        __syncthreads();
        cur ^= 1;
    }
#undef STAGE

    float w0 = 0.f, w1 = 0.f;
    if (mode == 1) { w0 = l0w[0]; w1 = l0w[1]; }
#pragma unroll
    for (int a = 0; a < 2; ++a) {
#pragma unroll
        for (int j = 0; j < 3; ++j) {
            int f = (wcol * 3 + j) * 16 + l15;
            if (f < NF) {
                if (mode == 0) {
                    int4 o;
#pragma unroll
                    for (int reg = 0; reg < 4; ++reg) {
                        int co = (wrow * 2 + a) * 16 + g * 4 + reg;
                        float vrq = acc[a][j][reg]     + b_r[co] - b_i[co];
                        float viq = acc[a + 2][j][reg] + b_r[co] + b_i[co];
                        ((int*)&o)[reg] = pack2(vrq, viq);
                    }
                    int co4 = (wrow * 2 + a) * 4 + g;
                    ((int4*)out_pk)[((size_t)((b * 16 + co4) * 64 + x0)) * 85 + f] = o;
                } else {
#pragma unroll
                    for (int reg = 0; reg < 4; ++reg) {
                        int co = (wrow * 2 + a) * 16 + g * 4 + reg;
                        float vrq = acc[a][j][reg]     + b_r[co] - b_i[co];
                        float viq = acc[a + 2][j][reg] + b_r[co] + b_i[co];
                        size_t o = ((size_t)(b * 64 + co) * 64 + x0) * NF + f;
                        yfull[o] += (fmaxf(vrq, 0.f) * w0 + fmaxf(viq, 0.f) * w1) * INV3;
                    }
                }
            }
        }
    }
}

// ---------------- K6: c0 1x1 complex conv via MFMA (packed hi/lo in, 3-term) ------------
__global__ __launch_bounds__(256, 4) void k_c0m(const int* __restrict__ Apk,
                                                const int* __restrict__ Apl,
                                                const short* __restrict__ wt,
                                                const float* __restrict__ b_r,
                                                const float* __restrict__ b_i,
                                                const float* __restrict__ l0w,
                                                float* __restrict__ yfull) {
    __shared__ __align__(16) short inT[100 * 80];  // 16,000 B
    int blk = blockIdx.x;
    int swz = (blk & 7) * (gridDim.x >> 3) + (blk >> 3);
    int b = swz >> 6, x0 = swz & 63;
    int tid = threadIdx.x;
    int lane = tid & 63, wid = tid >> 6;
    int wrow = wid & 1, wcol = wid >> 1;
    int l15 = lane & 15, g = lane >> 4;

    f32x4 acc[4][3];
#pragma unroll
    for (int a = 0; a < 4; ++a)
#pragma unroll
        for (int j = 0; j < 3; ++j) acc[a][j] = f32x4{0.f, 0.f, 0.f, 0.f};

    for (int chunk = 0; chunk < 4; ++chunk) {
        if (chunk > 0) __syncthreads();
        for (int idx = tid; idx < 340; idx += 256) {
            int f = idx % 85;
            int cg = idx / 85;
            size_t s4 = ((size_t)((b * 16 + chunk * 4 + cg) * 64 + x0)) * 85 + f;
            int4 dh = ((const int4*)Apk)[s4];
            int4 dl = ((const int4*)Apl)[s4];
            short* rowp = &inT[(f + 2) * 80];
            *(int4*)&rowp[cg * 8] = dh;
            *(int4*)&rowp[32 + cg * 8] = dl;
        }
        __syncthreads();
#pragma unroll
        for (int combo = 0; combo < 3; ++combo) {
            int wtap = (combo == 2) ? 1 : 0;
            int kkB = (combo == 1) ? 1 : 0;
            short8v afr[4];
#pragma unroll
            for (int a = 0; a < 4; ++a) {
                int tile = (a < 2) ? (wrow * 2 + a) : (wrow * 2 + a + 2);
                const short* ap = wt + ((((size_t)wtap * 4 + chunk) * 8 + tile) * 16 + l15) * 32 + g * 8;
                afr[a] = *(const short8v*)ap;
            }
            short8v bfr[3];
#pragma unroll
            for (int j = 0; j < 3; ++j) {
                int fs = (wcol * 3 + j) * 16 + l15 + 2;
                bfr[j] = *(const short8v*)&inT[fs * 80 + kkB * 32 + g * 8];
            }
#pragma unroll
            for (int a = 0; a < 4; ++a)
#pragma unroll
                for (int j = 0; j < 3; ++j)
                    acc[a][j] = __builtin_amdgcn_mfma_f32_16x16x32_bf16(afr[a], bfr[j],
                                                                        acc[a][j], 0, 0, 0);
        }
    }

    float w0 = l0w[0], w1 = l0w[1];
#pragma unroll
    for (int a = 0; a < 2; ++a) {
#pragma unroll
        for (int j = 0; j < 3; ++j) {
            int f = (wcol * 3 + j) * 16 + l15;
            if (f < NF) {
#pragma unroll
                for (int reg = 0; reg < 4; ++reg) {
                    int co = (wrow * 2 + a) * 16 + g * 4 + reg;
                    float vrq = acc[a][j][reg]     + b_r[co] - b_i[co];
                    float viq = acc[a + 2][j][reg] + b_r[co] + b_i[co];
                    size_t o = ((size_t)(b * 64 + co) * 64 + x0) * NF + f;
                    yfull[o] = (fmaxf(vrq, 0.f) * w0 + fmaxf(viq, 0.f) * w1) * INV3;
                }
            }
        }
    }
}

// ---------------- K8: mean over freq axis + l0 bias (coalesced, deterministic) ---------
__global__ __launch_bounds__(256) void k_reduce2(const float* __restrict__ yfull,
                                                 const float* __restrict__ l0b,
                                                 float* __restrict__ y2) {
    __shared__ float fs[3][85];
    int bn = blockIdx.x;   // b*64+n
    int tid = threadIdx.x;
    const float* p = yfull + (size_t)bn * 64 * 85;
    if (tid < 255) {
        int f = tid % 85, g = tid / 85;
        float s = 0.f;
        for (int x = g; x < 64; x += 3) s += p[x * 85 + f];
        fs[g][f] = s;
    }
    __syncthreads();
    if (tid < 85)
        y2[(size_t)bn * 85 + tid] = (fs[0][tid] + fs[1][tid] + fs[2][tid]) * (1.f / 64.f) + l0b[0];
}

// ---------------- K9: l2 (NF->ALL) + transpose + LayerNorm ----------------
__global__ __launch_bounds__(64) void k_l2ln(const float* __restrict__ y2,
                                             const float* __restrict__ l2w,
                                             const float* __restrict__ l2b,
                                             const float* __restrict__ g,
                                             const float* __restrict__ be,
                                             float* __restrict__ enc, int b0) {
    int bl = blockIdx.x / ALLT;
    int a = blockIdx.x % ALLT;
    int d = threadIdx.x;
    const float* wp = l2w + (size_t)a * NF;
    const float* yp = y2 + (size_t)(bl * 64 + d) * NF;
    float acc = l2b[a];
    for (int f = 0; f < NF; ++f) acc += yp[f] * wp[f];
    float s = acc, s2 = acc * acc;
    for (int m = 32; m >= 1; m >>= 1) { s += __shfl_xor(s, m); s2 += __shfl_xor(s2, m); }
    float mu = s * (1.f / 64.f);
    float var = s2 * (1.f / 64.f) - mu * mu;
    float rs = rsqrtf(var + 1e-5f);
    enc[((size_t)(b0 + bl) * ALLT + a) * DM + d] = (acc - mu) * rs * g[d] + be[d];
}

// ---------------- K10: T[b,ci,j] = sum_hx enc[b,ci,2hx+j-1]*l1w[hx] ----------------
__global__ __launch_bounds__(256) void k_T(const float* __restrict__ enc,
                                           const float* __restrict__ l1w,
                                           float* __restrict__ T) {
    int i = blockIdx.x * 256 + threadIdx.x;
    if (i >= Bt * ALLT * 3) return;
    int j = i % 3;
    int rest = i / 3;
    int ci = rest % ALLT;
    int b = rest / ALLT;
    const float* e = enc + ((size_t)b * ALLT + ci) * DM;
    float s = 0.f;
    for (int hx = 0; hx < 32; ++hx) {
        int p = 2 * hx + j - 1;
        if (p >= 0 && p < DM) s += e[p] * l1w[hx];
    }
    T[i] = s;
}

// ---------------- K11: seq_series[b,co] ----------------
__global__ __launch_bounds__(256) void k_seq(const float* __restrict__ T,
                                             const float* __restrict__ cvw,
                                             const float* __restrict__ cvb,
                                             const float* __restrict__ l1w,
                                             const float* __restrict__ l1b,
                                             float* __restrict__ out) {
    int i = blockIdx.x * 256 + threadIdx.x;
    if (i >= Bt * ALLT) return;
    int co = i % ALLT;
    int b = i / ALLT;
    float sl1 = 0.f;
    for (int hx = 0; hx < 32; ++hx) sl1 += l1w[hx];
    const float* tp = T + (size_t)b * ALLT * 3;
    const float* wp = cvw + (size_t)co * ALLT * 3;
    float s = 0.f;
    for (int q = 0; q < ALLT * 3; ++q) s += tp[q] * wp[q];
    out[i] = s + cvb[co] * sl1 + l1b[0];
}

// ---------------- K12: projection + denorm, last PRED steps ----------------
__global__ __launch_bounds__(256) void k_dec(const float* __restrict__ enc,
                                             const float* __restrict__ pw,
                                             const float* __restrict__ pb,
                                             const float* __restrict__ mean,
                                             const float* __restrict__ stdv,
                                             float* __restrict__ out) {
    int i = blockIdx.x * 256 + threadIdx.x;
    if (i >= Bt * PRED * CIN) return;
    int c = i % CIN;
    int rest = i / CIN;
    int tt = rest % PRED;
    int b = rest / PRED;
    const float* e = enc + ((size_t)b * ALLT + SEQ + tt) * DM;
    const float* w = pw + c * DM;
    float s = pb[c];
    for (int d = 0; d < DM; ++d) s += e[d] * w[d];
    out[i] = s * stdv[b * CIN + c] + mean[b * CIN + c];
}

extern "C" void kernel_launch(void* const* d_in, const int* in_sizes, int n_in,
                              void* d_out, int out_size, void* d_ws, size_t ws_size,
                              hipStream_t stream) {
    (void)in_sizes; (void)n_in; (void)out_size;
    const float* x_enc  = (const float*)d_in[0];
    const float* x_mark = (const float*)d_in[1];
    const float* tok_w  = (const float*)d_in[4];
    const float* temp_w = (const float*)d_in[5];
    const float* pl_w   = (const float*)d_in[6];
    const float* pl_b   = (const float*)d_in[7];
    const float* ln_g   = (const float*)d_in[8];
    const float* ln_b   = (const float*)d_in[9];
    const float* c0_wr  = (const float*)d_in[10];
    const float* c0_wi  = (const float*)d_in[11];
    const float* c0_br  = (const float*)d_in[12];
    const float* c0_bi  = (const float*)d_in[13];
    const float* cA_wr  = (const float*)d_in[14];
    const float* cA_wi  = (const float*)d_in[15];
    const float* cA_br  = (const float*)d_in[16];
    const float* cA_bi  = (const float*)d_in[17];
    const float* cB_wr  = (const float*)d_in[18];
    const float* cB_wi  = (const float*)d_in[19];
    const float* cB_br  = (const float*)d_in[20];
    const float* cB_bi  = (const float*)d_in[21];
    const float* l0_w   = (const float*)d_in[22];
    const float* l0_b   = (const float*)d_in[23];
    const float* l2_w   = (const float*)d_in[24];
    const float* l2_b   = (const float*)d_in[25];
    const float* cv_w   = (const float*)d_in[26];
    const float* cv_b   = (const float*)d_in[27];
    const float* l1_w   = (const float*)d_in[28];
    const float* l1_b   = (const float*)d_in[29];
    const float* proj_w = (const float*)d_in[30];
    const float* proj_b = (const float*)d_in[31];

    float* out0 = (float*)d_out;                    // dec: [32,336,7]
    float* out1 = out0 + (size_t)Bt * PRED * CIN;   // seq_series: [32,672]

    float* ws = (float*)d_ws;
    size_t off = 0;
    float* enc  = ws + off; off += (size_t)Bt * ALLT * DM;
    float* enc0 = ws + off; off += (size_t)Bt * SEQ * DM;
    float* mean = ws + off; off += 256;
    float* stdv = ws + off; off += 256;
    short* wtbuf = (short*)(ws + off); off += 622592;   // 1,245,184 bf16 packed weights

    const size_t perb = (size_t)DM * NFFT * NF;  // 348,160
    int Bc = 32;
    while (Bc > 1) {
        size_t need = (off + (size_t)Bc * DM * NF + 4 * (size_t)Bc * perb) * sizeof(float);
        if (need <= ws_size) break;
        Bc >>= 1;
    }
    float* y2 = ws + off; off += (size_t)Bc * DM * NF;
    float* yfull = ws + off; off += (size_t)Bc * perb;
    int*   Apk = (int*)(ws + off); off += (size_t)Bc * perb;
    int*   Apl = (int*)(ws + off); off += (size_t)Bc * perb;
    int*   Hpk = (int*)(ws + off); off += (size_t)Bc * perb;
    float* Tb = enc0;   // reuse: enc0 dead after k_plin2

    k_stats<<<Bt * CIN, 64, 0, stream>>>(x_enc, mean, stdv);
    k_wprep<<<(1245184 + 255) / 256, 256, 0, stream>>>(cA_wr, cA_wi, cB_wr, cB_wi,
                                                       c0_wr, c0_wi, wtbuf);
    k_embed<<<(Bt * SEQ * DM + 255) / 256, 256, 0, stream>>>(x_enc, x_mark, tok_w, temp_w,
                                                             mean, stdv, enc0);
    k_plin2<<<Bt * 14, 256, 0, stream>>>(enc0, pl_w, pl_b, enc);

    for (int l = 0; l < 2; ++l) {
        for (int b0 = 0; b0 < Bt; b0 += Bc) {
            k_stqka<<<Bc * 64, 256, 0, stream>>>(enc, b0, Apk, Apl);
            k_c0m<<<Bc * 64, 256, 0, stream>>>(Apk, Apl, wtbuf + 1179648 + (size_t)l * 32768,
                                               c0_br + l * 64, c0_bi + l * 64,
                                               l0_w + l * 2, yfull);
            for (int k = 1; k <= 2; ++k) {
                int convA = l * 4 + (k - 1) * 2;
                size_t boff = ((size_t)l * 2 + (k - 1)) * 64;
                k_conv3p<<<Bc * 64, 256, 0, stream>>>(Apk, wtbuf + (size_t)convA * 147456,
                                                      cA_br + boff, cA_bi + boff, k, 0,
                                                      l0_w + l * 2, Hpk, yfull);
                k_conv3p<<<Bc * 64, 256, 0, stream>>>(Hpk, wtbuf + (size_t)(convA + 1) * 147456,
                                                      cB_br + boff, cB_bi + boff, k, 1,
                                                      l0_w + l * 2, Hpk, yfull);
            }
            k_reduce2<<<Bc * 64, 256, 0, stream>>>(yfull, l0_b + l, y2);
            k_l2ln<<<Bc * ALLT, 64, 0, stream>>>(y2, l2_w + (size_t)l * ALLT * NF,
                                                 l2_b + (size_t)l * ALLT, ln_g, ln_b, enc, b0);
        }
    }

    k_T<<<(Bt * ALLT * 3 + 255) / 256, 256, 0, stream>>>(enc, l1_w, Tb);
    k_seq<<<(Bt * ALLT + 255) / 256, 256, 0, stream>>>(Tb, cv_w, cv_b, l1_w, l1_b, out1);
    k_dec<<<(Bt * PRED * CIN + 255) / 256, 256, 0, stream>>>(enc, proj_w, proj_b, mean, stdv, out0);
}

// Round 10
// 1369.097 us; speedup vs baseline: 1.2961x; 1.0768x over previous
//
#include <hip/hip_runtime.h>

typedef __attribute__((ext_vector_type(8))) short short8v;
typedef __attribute__((ext_vector_type(4))) float f32x4;
typedef __attribute__((ext_vector_type(16))) float f32x16;

static constexpr int Bt = 32;
static constexpr int SEQ = 336, PRED = 336, CIN = 7, ALLT = 672;
static constexpr int DM = 64, NFFT = 64, HOP = 8, NF = 85;
static constexpr int MARK = 4;
static constexpr float INV3 = 1.0f / 3.0f;

__device__ inline short f2bf(float v) {
    unsigned u = __float_as_uint(v);
    u += 0x7fffu + ((u >> 16) & 1u);   // round-to-nearest-even
    return (short)(u >> 16);
}
__device__ inline float bf2f(short h) {
    return __uint_as_float(((unsigned)(unsigned short)h) << 16);
}
__device__ inline int pack2(float r, float i) {
    return ((int)(unsigned short)f2bf(r)) | (((int)(unsigned short)f2bf(i)) << 16);
}
__device__ inline void async16(const int* g, short* l) {
    __builtin_amdgcn_global_load_lds(
        (const __attribute__((address_space(1))) unsigned int*)g,
        (__attribute__((address_space(3))) unsigned int*)l, 16, 0, 0);
}

// ---------------- K1: per (b,c) mean / std over time ----------------
__global__ __launch_bounds__(64) void k_stats(const float* __restrict__ x,
                                              float* __restrict__ mean,
                                              float* __restrict__ stdv) {
    int bc = blockIdx.x;              // b*7+c
    int b = bc / CIN, c = bc % CIN;
    int lane = threadIdx.x;
    float s = 0.f, s2 = 0.f;
    for (int t = lane; t < SEQ; t += 64) {
        float v = x[(b * SEQ + t) * CIN + c];
        s += v; s2 += v * v;
    }
    for (int m = 32; m >= 1; m >>= 1) { s += __shfl_xor(s, m); s2 += __shfl_xor(s2, m); }
    if (lane == 0) {
        float mu = s / SEQ;
        float var = s2 / SEQ - mu * mu;
        mean[bc] = mu;
        stdv[bc] = sqrtf(var + 1e-5f);
    }
}

// ---------------- K2: embedding (token conv + temporal + PE) ----------------
__global__ __launch_bounds__(256) void k_embed(const float* __restrict__ x,
                                               const float* __restrict__ mark,
                                               const float* __restrict__ tok_w,
                                               const float* __restrict__ temp_w,
                                               const float* __restrict__ mean,
                                               const float* __restrict__ stdv,
                                               float* __restrict__ enc0) {
    int i = blockIdx.x * 256 + threadIdx.x;
    if (i >= Bt * SEQ * DM) return;
    int d = i & 63;
    int t = (i >> 6) % SEQ;
    int b = i / (SEQ * DM);
    float val = 0.f;
    for (int c = 0; c < CIN; ++c) {
        float mu = mean[b * CIN + c];
        float is = 1.f / stdv[b * CIN + c];
        for (int j = 0; j < 3; ++j) {
            int tt = t + j - 1;
            if (tt < 0) tt += SEQ;
            if (tt >= SEQ) tt -= SEQ;
            float xv = (x[(b * SEQ + tt) * CIN + c] - mu) * is;
            val += xv * tok_w[(d * CIN + c) * 3 + j];
        }
    }
    float mk = 0.f;
    for (int m = 0; m < MARK; ++m) mk += mark[(b * SEQ + t) * MARK + m] * temp_w[d * MARK + m];
    float div = expf(-(float)(d & ~1) * (9.210340371976184f / (float)DM));
    float arg = (float)t * div;
    float pe = (d & 1) ? cosf(arg) : sinf(arg);
    enc0[i] = val + mk + pe;
}

// ---------------- K3: predict_linear (time 336 -> 672), LDS-blocked ----------------
__global__ __launch_bounds__(256) void k_plin2(const float* __restrict__ enc0,
                                               const float* __restrict__ pl_w,
                                               const float* __restrict__ pl_b,
                                               float* __restrict__ enc) {
    __shared__ float Et[56 * 64];     // [t][d]
    __shared__ float Wt[56 * 49];     // [t][a], pad 49
    int blk = blockIdx.x;
    int b = blk / 14, at = blk % 14;
    int abase = at * 48;
    int tid = threadIdx.x;
    int a0 = (tid & 15) * 3;
    int d0 = (tid >> 4) * 4;
    float acc[3][4];
#pragma unroll
    for (int q = 0; q < 3; ++q)
#pragma unroll
        for (int r = 0; r < 4; ++r) acc[q][r] = 0.f;
    for (int tc = 0; tc < 6; ++tc) {
        if (tc) __syncthreads();
        for (int i = tid; i < 56 * 64; i += 256)
            Et[i] = enc0[((size_t)b * SEQ + tc * 56) * DM + i];
        for (int i = tid; i < 48 * 56; i += 256) {
            int r = i / 56, c = i - r * 56;
            Wt[c * 49 + r] = pl_w[(size_t)(abase + r) * SEQ + tc * 56 + c];
        }
        __syncthreads();
#pragma unroll 4
        for (int t = 0; t < 56; ++t) {
            float4 e = *(const float4*)&Et[t * 64 + d0];
            float w0 = Wt[t * 49 + a0];
            float w1 = Wt[t * 49 + a0 + 1];
            float w2 = Wt[t * 49 + a0 + 2];
            acc[0][0] += w0 * e.x; acc[0][1] += w0 * e.y;
            acc[0][2] += w0 * e.z; acc[0][3] += w0 * e.w;
            acc[1][0] += w1 * e.x; acc[1][1] += w1 * e.y;
            acc[1][2] += w1 * e.z; acc[1][3] += w1 * e.w;
            acc[2][0] += w2 * e.x; acc[2][1] += w2 * e.y;
            acc[2][2] += w2 * e.z; acc[2][3] += w2 * e.w;
        }
    }
#pragma unroll
    for (int q = 0; q < 3; ++q) {
        int a = abase + a0 + q;
        float bias = pl_b[a];
        float4 o = {acc[q][0] + bias, acc[q][1] + bias, acc[q][2] + bias, acc[q][3] + bias};
        *(float4*)&enc[((size_t)b * ALLT + a) * DM + d0] = o;
    }
}

// ---------------- K4+K5 fused: STFT (MFMA DFT) + qk + sigmoid + a = gS ----------------
// One block per (bl, n), XCD-swizzled so n-quads share an L2. Output packed bf16 Apk.
__global__ __launch_bounds__(256) void k_stqka(const float* __restrict__ enc, int b0,
                                               int* __restrict__ Apk) {
    __shared__ __align__(16) short L[54272];   // 108,544 B, two overlaid regions
    // region A (staging for DFT)
    constexpr int TCH = 0, TCL = 4608, TSH = 9216, TSL = 13824;   // twiddle [64][72]
    constexpr int XWH = 18432, XWL = 25344;                       // frames  [96][72]
    float* xp  = (float*)&L[32256];   // [736]
    float* twc = (float*)&L[33728];   // [64]
    float* tws = (float*)&L[33984];   // [64]
    // region B (compute) — overlays region A after DFT
    constexpr int SRH = 0, SIH = 6656, SRL = 13312, SIL = 19968;        // rows [64][104]
    constexpr int STRH = 26624, STRL = 33536, STIH = 40448, STIL = 47360;  // ST [96][72]
    constexpr int GRH = 0, GRL = 4608, GIH = 9216, GIL = 13824;         // g [64][72] overlay

    int blk = blockIdx.x;
    int bn = (blk & 7) * (gridDim.x >> 3) + (blk >> 3);   // XCD-contiguous chunks
    int bl = bn >> 6, n = bn & 63;
    int bg = b0 + bl;
    int tid = threadIdx.x;
    int lane = tid & 63, w = tid >> 6;
    int l31 = lane & 31, kg = lane >> 5;

    // --- 1) reflect-padded series + base twiddle tables ---
    for (int i = tid; i < ALLT + NFFT; i += 256) {
        int j = i - 32;
        if (j < 0) j = -j;
        if (j > ALLT - 1) j = 2 * (ALLT - 1) - j;
        xp[i] = enc[((size_t)bg * ALLT + j) * DM + n];
    }
    if (tid < 64) {
        float ang = (6.283185307179586f / 64.f) * (float)tid;
        twc[tid] = cosf(ang);
        tws[tid] = sinf(ang);
    }
    __syncthreads();
    // --- 2) twiddle matrices W[k][tt] split hi/lo ---
    for (int i = tid; i < 64 * 64; i += 256) {
        int k = i >> 6, tt = i & 63;
        int m = (k * tt) & 63;
        float c = twc[m], s = tws[m];
        short ch = f2bf(c); short cl = f2bf(c - bf2f(ch));
        short sh = f2bf(s); short sl = f2bf(s - bf2f(sh));
        int o = k * 72 + tt;
        L[TCH + o] = ch; L[TCL + o] = cl; L[TSH + o] = sh; L[TSL + o] = sl;
    }
    // --- 3) windowed frames xw[f][tt] split hi/lo (f>=85 zero) ---
    for (int i = tid; i < 96 * 64; i += 256) {
        int f = i >> 6, tt = i & 63;
        float v = 0.f;
        if (f < 85) v = xp[f * HOP + tt] * (0.5f - 0.5f * twc[tt]) * 0.125f;
        short vh = f2bf(v); short vl = f2bf(v - bf2f(vh));
        int o = f * 72 + tt;
        L[XWH + o] = vh; L[XWL + o] = vl;
    }
    __syncthreads();

    // --- 4) DFT via split-bf16 MFMA: S[k][f] = sum_tt W[k][tt]*xw[f][tt] ---
    int kt = w & 1;
    int ftA = (w < 2) ? 0 : 2;
    f32x16 srA, siA, srB, siB;
#pragma unroll
    for (int r = 0; r < 16; ++r) { srA[r] = 0.f; siA[r] = 0.f; srB[r] = 0.f; siB[r] = 0.f; }
#pragma unroll
    for (int tts = 0; tts < 4; ++tts) {
        int ko = (kt * 32 + l31) * 72 + tts * 16 + kg * 8;
        short8v ach = *(const short8v*)&L[TCH + ko];
        short8v acl = *(const short8v*)&L[TCL + ko];
        short8v ash = *(const short8v*)&L[TSH + ko];
        short8v asl = *(const short8v*)&L[TSL + ko];
        {
            int bo = (ftA * 32 + l31) * 72 + tts * 16 + kg * 8;
            short8v bh = *(const short8v*)&L[XWH + bo];
            short8v bl_ = *(const short8v*)&L[XWL + bo];
            srA = __builtin_amdgcn_mfma_f32_32x32x16_bf16(ach, bh, srA, 0, 0, 0);
            srA = __builtin_amdgcn_mfma_f32_32x32x16_bf16(acl, bh, srA, 0, 0, 0);
            srA = __builtin_amdgcn_mfma_f32_32x32x16_bf16(ach, bl_, srA, 0, 0, 0);
            siA = __builtin_amdgcn_mfma_f32_32x32x16_bf16(ash, bh, siA, 0, 0, 0);
            siA = __builtin_amdgcn_mfma_f32_32x32x16_bf16(asl, bh, siA, 0, 0, 0);
            siA = __builtin_amdgcn_mfma_f32_32x32x16_bf16(ash, bl_, siA, 0, 0, 0);
        }
        if (w < 2) {
            int bo = (32 + l31) * 72 + tts * 16 + kg * 8;   // ft = 1
            short8v bh = *(const short8v*)&L[XWH + bo];
            short8v bl_ = *(const short8v*)&L[XWL + bo];
            srB = __builtin_amdgcn_mfma_f32_32x32x16_bf16(ach, bh, srB, 0, 0, 0);
            srB = __builtin_amdgcn_mfma_f32_32x32x16_bf16(acl, bh, srB, 0, 0, 0);
            srB = __builtin_amdgcn_mfma_f32_32x32x16_bf16(ach, bl_, srB, 0, 0, 0);
            siB = __builtin_amdgcn_mfma_f32_32x32x16_bf16(ash, bh, siB, 0, 0, 0);
            siB = __builtin_amdgcn_mfma_f32_32x32x16_bf16(asl, bh, siB, 0, 0, 0);
            siB = __builtin_amdgcn_mfma_f32_32x32x16_bf16(ash, bl_, siB, 0, 0, 0);
        }
    }
    __syncthreads();   // region A dead; write region B

    // --- 5) write S: row-major per-element (free) + transposed b64-packed ---
    {
        int fA = ftA * 32 + l31;
#pragma unroll
        for (int rg = 0; rg < 4; ++rg) {
            int k0 = kt * 32 + 8 * rg + 4 * kg;
            short prh[4], prl[4], pih[4], pil[4];
#pragma unroll
            for (int q = 0; q < 4; ++q) {
                int r = rg * 4 + q;
                float sv = srA[r], iv = -siA[r];
                short rh = f2bf(sv); short rl = f2bf(sv - bf2f(rh));
                short ih = f2bf(iv); short il = f2bf(iv - bf2f(ih));
                prh[q] = rh; prl[q] = rl; pih[q] = ih; pil[q] = il;
                L[SRH + (k0 + q) * 104 + fA] = rh; L[SRL + (k0 + q) * 104 + fA] = rl;
                L[SIH + (k0 + q) * 104 + fA] = ih; L[SIL + (k0 + q) * 104 + fA] = il;
            }
            *(long long*)&L[STRH + fA * 72 + k0] = *(long long*)prh;
            *(long long*)&L[STRL + fA * 72 + k0] = *(long long*)prl;
            *(long long*)&L[STIH + fA * 72 + k0] = *(long long*)pih;
            *(long long*)&L[STIL + fA * 72 + k0] = *(long long*)pil;
        }
        if (w < 2) {
            int fB = 32 + l31;
#pragma unroll
            for (int rg = 0; rg < 4; ++rg) {
                int k0 = kt * 32 + 8 * rg + 4 * kg;
                short prh[4], prl[4], pih[4], pil[4];
#pragma unroll
                for (int q = 0; q < 4; ++q) {
                    int r = rg * 4 + q;
                    float sv = srB[r], iv = -siB[r];
                    short rh = f2bf(sv); short rl = f2bf(sv - bf2f(rh));
                    short ih = f2bf(iv); short il = f2bf(iv - bf2f(ih));
                    prh[q] = rh; prl[q] = rl; pih[q] = ih; pil[q] = il;
                    L[SRH + (k0 + q) * 104 + fB] = rh; L[SRL + (k0 + q) * 104 + fB] = rl;
                    L[SIH + (k0 + q) * 104 + fB] = ih; L[SIL + (k0 + q) * 104 + fB] = il;
                }
                *(long long*)&L[STRH + fB * 72 + k0] = *(long long*)prh;
                *(long long*)&L[STRL + fB * 72 + k0] = *(long long*)prl;
                *(long long*)&L[STIH + fB * 72 + k0] = *(long long*)pih;
                *(long long*)&L[STIL + fB * 72 + k0] = *(long long*)pil;
            }
        }
    }
    __syncthreads();

    // --- 6) phase 1: qk (split-bf16, 3-term) ---
    int mh = w >> 1, nh = w & 1;
    f32x16 P, Q, R;
#pragma unroll
    for (int r = 0; r < 16; ++r) { P[r] = 0.f; Q[r] = 0.f; R[r] = 0.f; }
#pragma unroll
    for (int f0 = 0; f0 < 96; f0 += 16) {
        int ka = f0 + kg * 8;
        int ra = (mh * 32 + l31) * 104 + ka;
        int rb = (nh * 32 + l31) * 104 + ka;
        short8v a_rh = *(const short8v*)&L[SRH + ra];
        short8v a_rl = *(const short8v*)&L[SRL + ra];
        short8v a_ih = *(const short8v*)&L[SIH + ra];
        short8v a_il = *(const short8v*)&L[SIL + ra];
        short8v b_rh = *(const short8v*)&L[SRH + rb];
        short8v b_rl = *(const short8v*)&L[SRL + rb];
        short8v b_ih = *(const short8v*)&L[SIH + rb];
        short8v b_il = *(const short8v*)&L[SIL + rb];
        P = __builtin_amdgcn_mfma_f32_32x32x16_bf16(a_rh, b_rh, P, 0, 0, 0);
        P = __builtin_amdgcn_mfma_f32_32x32x16_bf16(a_rl, b_rh, P, 0, 0, 0);
        P = __builtin_amdgcn_mfma_f32_32x32x16_bf16(a_rh, b_rl, P, 0, 0, 0);
        Q = __builtin_amdgcn_mfma_f32_32x32x16_bf16(a_ih, b_ih, Q, 0, 0, 0);
        Q = __builtin_amdgcn_mfma_f32_32x32x16_bf16(a_il, b_ih, Q, 0, 0, 0);
        Q = __builtin_amdgcn_mfma_f32_32x32x16_bf16(a_ih, b_il, Q, 0, 0, 0);
        R = __builtin_amdgcn_mfma_f32_32x32x16_bf16(a_rh, b_ih, R, 0, 0, 0);
        R = __builtin_amdgcn_mfma_f32_32x32x16_bf16(a_rl, b_ih, R, 0, 0, 0);
        R = __builtin_amdgcn_mfma_f32_32x32x16_bf16(a_rh, b_il, R, 0, 0, 0);
        R = __builtin_amdgcn_mfma_f32_32x32x16_bf16(a_ih, b_rh, R, 0, 0, 0);
        R = __builtin_amdgcn_mfma_f32_32x32x16_bf16(a_il, b_rh, R, 0, 0, 0);
        R = __builtin_amdgcn_mfma_f32_32x32x16_bf16(a_ih, b_rl, R, 0, 0, 0);
    }
    __syncthreads();   // row arrays dead; g overlays them

    {
        int y = nh * 32 + l31;
#pragma unroll
        for (int r = 0; r < 16; ++r) {
            int x = mh * 32 + (r & 3) + 8 * (r >> 2) + 4 * kg;
            float gr = 1.f / (1.f + __expf(-(P[r] - Q[r])));
            float gi = 1.f / (1.f + __expf(-R[r]));
            short gh = f2bf(gr); short gl = f2bf(gr - bf2f(gh));
            short jh = f2bf(gi); short jl = f2bf(gi - bf2f(jh));
            L[GRH + x * 72 + y] = gh; L[GRL + x * 72 + y] = gl;
            L[GIH + x * 72 + y] = jh; L[GIL + x * 72 + y] = jl;
        }
    }
    __syncthreads();

    // --- 7) phase 2: a^T[z,x] = sum_y S[y,z] g[x,y] (complex, full split) ---
    int mg = w >> 1;
    int mtA = (mg == 0) ? 0 : 2;
    f32x16 u1A, u2A, u3A, u1B, u2B, u3B;
#pragma unroll
    for (int r = 0; r < 16; ++r) {
        u1A[r] = 0.f; u2A[r] = 0.f; u3A[r] = 0.f;
        u1B[r] = 0.f; u2B[r] = 0.f; u3B[r] = 0.f;
    }
#pragma unroll
    for (int y0 = 0; y0 < 64; y0 += 16) {
        int kb = y0 + kg * 8;
        int gb = (nh * 32 + l31) * 72 + kb;
        short8v bgrh = *(const short8v*)&L[GRH + gb];
        short8v bgrl = *(const short8v*)&L[GRL + gb];
        short8v bgih = *(const short8v*)&L[GIH + gb];
        short8v bgil = *(const short8v*)&L[GIL + gb];
        {
            int sa = (mtA * 32 + l31) * 72 + kb;
            short8v arh = *(const short8v*)&L[STRH + sa];
            short8v arl = *(const short8v*)&L[STRL + sa];
            short8v aih = *(const short8v*)&L[STIH + sa];
            short8v ail = *(const short8v*)&L[STIL + sa];
            u1A = __builtin_amdgcn_mfma_f32_32x32x16_bf16(arh, bgrh, u1A, 0, 0, 0);
            u1A = __builtin_amdgcn_mfma_f32_32x32x16_bf16(arl, bgrh, u1A, 0, 0, 0);
            u1A = __builtin_amdgcn_mfma_f32_32x32x16_bf16(arh, bgrl, u1A, 0, 0, 0);
            u2A = __builtin_amdgcn_mfma_f32_32x32x16_bf16(aih, bgih, u2A, 0, 0, 0);
            u2A = __builtin_amdgcn_mfma_f32_32x32x16_bf16(ail, bgih, u2A, 0, 0, 0);
            u2A = __builtin_amdgcn_mfma_f32_32x32x16_bf16(aih, bgil, u2A, 0, 0, 0);
            u3A = __builtin_amdgcn_mfma_f32_32x32x16_bf16(aih, bgrh, u3A, 0, 0, 0);
            u3A = __builtin_amdgcn_mfma_f32_32x32x16_bf16(ail, bgrh, u3A, 0, 0, 0);
            u3A = __builtin_amdgcn_mfma_f32_32x32x16_bf16(aih, bgrl, u3A, 0, 0, 0);
            u3A = __builtin_amdgcn_mfma_f32_32x32x16_bf16(arh, bgih, u3A, 0, 0, 0);
            u3A = __builtin_amdgcn_mfma_f32_32x32x16_bf16(arl, bgih, u3A, 0, 0, 0);
            u3A = __builtin_amdgcn_mfma_f32_32x32x16_bf16(arh, bgil, u3A, 0, 0, 0);
        }
        if (mg == 0) {
            int sa = (1 * 32 + l31) * 72 + kb;
            short8v arh = *(const short8v*)&L[STRH + sa];
            short8v arl = *(const short8v*)&L[STRL + sa];
            short8v aih = *(const short8v*)&L[STIH + sa];
            short8v ail = *(const short8v*)&L[STIL + sa];
            u1B = __builtin_amdgcn_mfma_f32_32x32x16_bf16(arh, bgrh, u1B, 0, 0, 0);
            u1B = __builtin_amdgcn_mfma_f32_32x32x16_bf16(arl, bgrh, u1B, 0, 0, 0);
            u1B = __builtin_amdgcn_mfma_f32_32x32x16_bf16(arh, bgrl, u1B, 0, 0, 0);
            u2B = __builtin_amdgcn_mfma_f32_32x32x16_bf16(aih, bgih, u2B, 0, 0, 0);
            u2B = __builtin_amdgcn_mfma_f32_32x32x16_bf16(ail, bgih, u2B, 0, 0, 0);
            u2B = __builtin_amdgcn_mfma_f32_32x32x16_bf16(aih, bgil, u2B, 0, 0, 0);
            u3B = __builtin_amdgcn_mfma_f32_32x32x16_bf16(aih, bgrh, u3B, 0, 0, 0);
            u3B = __builtin_amdgcn_mfma_f32_32x32x16_bf16(ail, bgrh, u3B, 0, 0, 0);
            u3B = __builtin_amdgcn_mfma_f32_32x32x16_bf16(aih, bgrl, u3B, 0, 0, 0);
            u3B = __builtin_amdgcn_mfma_f32_32x32x16_bf16(arh, bgih, u3B, 0, 0, 0);
            u3B = __builtin_amdgcn_mfma_f32_32x32x16_bf16(arl, bgih, u3B, 0, 0, 0);
            u3B = __builtin_amdgcn_mfma_f32_32x32x16_bf16(arh, bgil, u3B, 0, 0, 0);
        }
    }
    // --- 8) store packed bf16 a (hi only) ---
    {
        size_t pkbase = ((size_t)(bl * 16 + (n >> 2)) * 64) * 85 * 4 + (n & 3);
        int x2 = nh * 32 + l31;
#pragma unroll
        for (int r = 0; r < 16; ++r) {
            int z = mtA * 32 + (r & 3) + 8 * (r >> 2) + 4 * kg;
            if (z < 85)
                Apk[pkbase + ((size_t)x2 * 85 + z) * 4] = pack2(u1A[r] - u2A[r], u3A[r]);
        }
        if (mg == 0) {
#pragma unroll
            for (int r = 0; r < 16; ++r) {
                int z = 32 + (r & 3) + 8 * (r >> 2) + 4 * kg;
                Apk[pkbase + ((size_t)x2 * 85 + z) * 4] = pack2(u1B[r] - u2B[r], u3B[r]);
            }
        }
    }
}

// ---------------- K-wprep: pack complex conv weights into MFMA A-layout ----------------
// 3x3 convs c 0..7: [conv][tap 9][chunk 4][tile 8][16][32] (1,179,648).
// c0 l=0,1 at 1,179,648: [l][wtap 2 (hi,lo)][chunk 4][tile 8][16][32] (65,536).
__global__ __launch_bounds__(256) void k_wprep(const float* __restrict__ cA_wr,
                                               const float* __restrict__ cA_wi,
                                               const float* __restrict__ cB_wr,
                                               const float* __restrict__ cB_wi,
                                               const float* __restrict__ c0_wr,
                                               const float* __restrict__ c0_wi,
                                               short* __restrict__ wt) {
    int idx = blockIdx.x * 256 + threadIdx.x;
    if (idx >= 1245184) return;
    int c32 = idx & 31;
    int m = (idx >> 5) & 127;
    int ci_l = c32 >> 1;
    int part = c32 & 1;
    int co = m & 63;
    const float *wr, *wi;
    size_t woff;
    bool lo = false;
    int chunk;
    if (idx < 1179648) {
        chunk = (idx >> 12) & 3;
        int tap = (idx >> 14) % 9;
        int conv = idx / 147456;
        int l = conv >> 2, k1 = (conv >> 1) & 1, ab = conv & 1;
        int ci = chunk * 16 + ci_l;
        woff = (((size_t)(l * 2 + k1) * 64 + co) * 64 + ci) * 9 + tap;
        wr = ab ? cB_wr : cA_wr;
        wi = ab ? cB_wi : cA_wi;
    } else {
        int i2 = idx - 1179648;
        chunk = (i2 >> 12) & 3;
        lo = (i2 >> 14) & 1;
        int l = i2 >> 15;
        int ci = chunk * 16 + ci_l;
        woff = ((size_t)(l * 64 + co)) * 64 + ci;
        wr = c0_wr; wi = c0_wi;
    }
    float a = wr[woff], bb = wi[woff];
    float v = (m < 64) ? (part ? -bb : a) : (part ? a : bb);
    if (lo) v = v - bf2f(f2bf(v));
    wt[idx] = f2bf(v);
}

// ---------------- K7: complex 3x3 dilated conv, packed bf16, global_load_lds + dbuf ----
__global__ __launch_bounds__(256, 4) void k_conv3p(const int* __restrict__ in_pk,
                                                   const short* __restrict__ wt,
                                                   const float* __restrict__ b_r,
                                                   const float* __restrict__ b_i,
                                                   int K, int mode,
                                                   const float* __restrict__ l0w,
                                                   int* __restrict__ out_pk,
                                                   float* __restrict__ yfull) {
    __shared__ __align__(16) short inT[2][1020 * 8];   // 2 x 16,320 B
    int blk = blockIdx.x;
    int swz = (blk & 7) * (gridDim.x >> 3) + (blk >> 3);   // XCD-contiguous (grid%8==0)
    int b = swz >> 6, x0 = swz & 63;
    int tid = threadIdx.x;
    int lane = tid & 63, wid = tid >> 6;
    int wrow = wid & 1, wcol = wid >> 1;
    int l15 = lane & 15, g = lane >> 4;

#define STAGE(CC, BUFI)                                                       \
    do {                                                                      \
        _Pragma("unroll")                                                     \
        for (int it = 0; it < 4; ++it) {                                      \
            int idx = tid + it * 256;                                         \
            if (idx < 1020) {                                                 \
                int f = idx % 85;                                             \
                int rc = idx / 85;                                            \
                int xr = rc >> 2, cg = rc & 3;                                \
                int xg = x0 + (xr - 1) * K;                                   \
                if ((unsigned)xg < 64u) {                                     \
                    const int* src = in_pk +                                  \
                        (((size_t)((b * 16 + (CC) * 4 + cg) * 64 + xg)) * 85 + f) * 4; \
                    async16(src, &inT[BUFI][(wid * 64 + it * 256) * 8]);      \
                }                                                             \
            }                                                                 \
        }                                                                     \
    } while (0)

    { int* p = (int*)&inT[0][0];
      for (int i = tid; i < 2 * 1020 * 4; i += 256) p[i] = 0; }
    __syncthreads();

    f32x4 acc[4][3];
#pragma unroll
    for (int a = 0; a < 4; ++a)
#pragma unroll
        for (int j = 0; j < 3; ++j) acc[a][j] = f32x4{0.f, 0.f, 0.f, 0.f};

    STAGE(0, 0);
    __syncthreads();

    int cur = 0;
    for (int chunk = 0; chunk < 4; ++chunk) {
        if (chunk == 0) STAGE(1, 1);
        else if (chunk == 1) STAGE(2, 0);
        else if (chunk == 2) STAGE(3, 1);
        const short* bb = &inT[cur][0];
#pragma unroll
        for (int u = 0; u < 3; ++u) {
#pragma unroll
            for (int v = 0; v < 3; ++v) {
                int tap = u * 3 + v;
                short8v afr[4];
#pragma unroll
                for (int a = 0; a < 4; ++a) {
                    int tile = (a < 2) ? (wrow * 2 + a) : (wrow * 2 + a + 2);
                    const short* ap = wt + ((((size_t)tap * 4 + chunk) * 8 + tile) * 16 + l15) * 32 + g * 8;
                    afr[a] = *(const short8v*)ap;
                }
                short8v bfr[3];
#pragma unroll
                for (int j = 0; j < 3; ++j) {
                    int fs = (wcol * 3 + j) * 16 + l15 + (v - 1) * K;
                    bool inr = ((unsigned)fs < 85u);
                    int fsc = inr ? fs : 0;
                    short8v t8 = *(const short8v*)&bb[((u * 4 + g) * 85 + fsc) * 8];
                    bfr[j] = inr ? t8 : short8v{0, 0, 0, 0, 0, 0, 0, 0};
                }
#pragma unroll
                for (int a = 0; a < 4; ++a)
#pragma unroll
                    for (int j = 0; j < 3; ++j)
                        acc[a][j] = __builtin_amdgcn_mfma_f32_16x16x32_bf16(afr[a], bfr[j],
                                                                            acc[a][j], 0, 0, 0);
            }
        }
        __syncthreads();
        cur ^= 1;
    }
#undef STAGE

    float w0 = 0.f, w1 = 0.f;
    if (mode == 1) { w0 = l0w[0]; w1 = l0w[1]; }
#pragma unroll
    for (int a = 0; a < 2; ++a) {
#pragma unroll
        for (int j = 0; j < 3; ++j) {
            int f = (wcol * 3 + j) * 16 + l15;
            if (f < NF) {
                if (mode == 0) {
                    int4 o;
#pragma unroll
                    for (int reg = 0; reg < 4; ++reg) {
                        int co = (wrow * 2 + a) * 16 + g * 4 + reg;
                        float vrq = acc[a][j][reg]     + b_r[co] - b_i[co];
                        float viq = acc[a + 2][j][reg] + b_r[co] + b_i[co];
                        ((int*)&o)[reg] = pack2(vrq, viq);
                    }
                    int co4 = (wrow * 2 + a) * 4 + g;
                    ((int4*)out_pk)[((size_t)((b * 16 + co4) * 64 + x0)) * 85 + f] = o;
                } else {
#pragma unroll
                    for (int reg = 0; reg < 4; ++reg) {
                        int co = (wrow * 2 + a) * 16 + g * 4 + reg;
                        float vrq = acc[a][j][reg]     + b_r[co] - b_i[co];
                        float viq = acc[a + 2][j][reg] + b_r[co] + b_i[co];
                        size_t o = ((size_t)(b * 64 + co) * 64 + x0) * NF + f;
                        yfull[o] += (fmaxf(vrq, 0.f) * w0 + fmaxf(viq, 0.f) * w1) * INV3;
                    }
                }
            }
        }
    }
}

// ---------------- K6: c0 1x1 complex conv via MFMA (packed bf16 in, 2-term weight) -----
__global__ __launch_bounds__(256, 4) void k_c0m(const int* __restrict__ Apk,
                                                const short* __restrict__ wt,
                                                const float* __restrict__ b_r,
                                                const float* __restrict__ b_i,
                                                const float* __restrict__ l0w,
                                                float* __restrict__ yfull) {
    __shared__ __align__(16) short inT[100 * 40];  // 8,000 B
    int blk = blockIdx.x;
    int swz = (blk & 7) * (gridDim.x >> 3) + (blk >> 3);
    int b = swz >> 6, x0 = swz & 63;
    int tid = threadIdx.x;
    int lane = tid & 63, wid = tid >> 6;
    int wrow = wid & 1, wcol = wid >> 1;
    int l15 = lane & 15, g = lane >> 4;

    f32x4 acc[4][3];
#pragma unroll
    for (int a = 0; a < 4; ++a)
#pragma unroll
        for (int j = 0; j < 3; ++j) acc[a][j] = f32x4{0.f, 0.f, 0.f, 0.f};

    for (int chunk = 0; chunk < 4; ++chunk) {
        if (chunk > 0) __syncthreads();
        for (int idx = tid; idx < 340; idx += 256) {
            int f = idx % 85;
            int cg = idx / 85;
            size_t s4 = ((size_t)((b * 16 + chunk * 4 + cg) * 64 + x0)) * 85 + f;
            int4 dh = ((const int4*)Apk)[s4];
            *(int4*)&inT[(f + 2) * 40 + cg * 8] = dh;
        }
        __syncthreads();
#pragma unroll
        for (int wtap = 0; wtap < 2; ++wtap) {
            short8v afr[4];
#pragma unroll
            for (int a = 0; a < 4; ++a) {
                int tile = (a < 2) ? (wrow * 2 + a) : (wrow * 2 + a + 2);
                const short* ap = wt + ((((size_t)wtap * 4 + chunk) * 8 + tile) * 16 + l15) * 32 + g * 8;
                afr[a] = *(const short8v*)ap;
            }
            short8v bfr[3];
#pragma unroll
            for (int j = 0; j < 3; ++j) {
                int fs = (wcol * 3 + j) * 16 + l15 + 2;
                bfr[j] = *(const short8v*)&inT[fs * 40 + g * 8];
            }
#pragma unroll
            for (int a = 0; a < 4; ++a)
#pragma unroll
                for (int j = 0; j < 3; ++j)
                    acc[a][j] = __builtin_amdgcn_mfma_f32_16x16x32_bf16(afr[a], bfr[j],
                                                                        acc[a][j], 0, 0, 0);
        }
    }

    float w0 = l0w[0], w1 = l0w[1];
#pragma unroll
    for (int a = 0; a < 2; ++a) {
#pragma unroll
        for (int j = 0; j < 3; ++j) {
            int f = (wcol * 3 + j) * 16 + l15;
            if (f < NF) {
#pragma unroll
                for (int reg = 0; reg < 4; ++reg) {
                    int co = (wrow * 2 + a) * 16 + g * 4 + reg;
                    float vrq = acc[a][j][reg]     + b_r[co] - b_i[co];
                    float viq = acc[a + 2][j][reg] + b_r[co] + b_i[co];
                    size_t o = ((size_t)(b * 64 + co) * 64 + x0) * NF + f;
                    yfull[o] = (fmaxf(vrq, 0.f) * w0 + fmaxf(viq, 0.f) * w1) * INV3;
                }
            }
        }
    }
}

// ---------------- K8: mean over freq axis + l0 bias (coalesced, deterministic) ---------
__global__ __launch_bounds__(256) void k_reduce2(const float* __restrict__ yfull,
                                                 const float* __restrict__ l0b,
                                                 float* __restrict__ y2) {
    __shared__ float fs[3][85];
    int bn = blockIdx.x;   // b*64+n
    int tid = threadIdx.x;
    const float* p = yfull + (size_t)bn * 64 * 85;
    if (tid < 255) {
        int f = tid % 85, g = tid / 85;
        float s = 0.f;
        for (int x = g; x < 64; x += 3) s += p[x * 85 + f];
        fs[g][f] = s;
    }
    __syncthreads();
    if (tid < 85)
        y2[(size_t)bn * 85 + tid] = (fs[0][tid] + fs[1][tid] + fs[2][tid]) * (1.f / 64.f) + l0b[0];
}

// ---------------- K9: l2 (NF->ALL) + transpose + LayerNorm ----------------
__global__ __launch_bounds__(64) void k_l2ln(const float* __restrict__ y2,
                                             const float* __restrict__ l2w,
                                             const float* __restrict__ l2b,
                                             const float* __restrict__ g,
                                             const float* __restrict__ be,
                                             float* __restrict__ enc, int b0) {
    int bl = blockIdx.x / ALLT;
    int a = blockIdx.x % ALLT;
    int d = threadIdx.x;
    const float* wp = l2w + (size_t)a * NF;
    const float* yp = y2 + (size_t)(bl * 64 + d) * NF;
    float acc = l2b[a];
    for (int f = 0; f < NF; ++f) acc += yp[f] * wp[f];
    float s = acc, s2 = acc * acc;
    for (int m = 32; m >= 1; m >>= 1) { s += __shfl_xor(s, m); s2 += __shfl_xor(s2, m); }
    float mu = s * (1.f / 64.f);
    float var = s2 * (1.f / 64.f) - mu * mu;
    float rs = rsqrtf(var + 1e-5f);
    enc[((size_t)(b0 + bl) * ALLT + a) * DM + d] = (acc - mu) * rs * g[d] + be[d];
}

// ---------------- K10: T[b,ci,j] = sum_hx enc[b,ci,2hx+j-1]*l1w[hx] ----------------
__global__ __launch_bounds__(256) void k_T(const float* __restrict__ enc,
                                           const float* __restrict__ l1w,
                                           float* __restrict__ T) {
    int i = blockIdx.x * 256 + threadIdx.x;
    if (i >= Bt * ALLT * 3) return;
    int j = i % 3;
    int rest = i / 3;
    int ci = rest % ALLT;
    int b = rest / ALLT;
    const float* e = enc + ((size_t)b * ALLT + ci) * DM;
    float s = 0.f;
    for (int hx = 0; hx < 32; ++hx) {
        int p = 2 * hx + j - 1;
        if (p >= 0 && p < DM) s += e[p] * l1w[hx];
    }
    T[i] = s;
}

// ---------------- K11: seq_series[b,co] ----------------
__global__ __launch_bounds__(256) void k_seq(const float* __restrict__ T,
                                             const float* __restrict__ cvw,
                                             const float* __restrict__ cvb,
                                             const float* __restrict__ l1w,
                                             const float* __restrict__ l1b,
                                             float* __restrict__ out) {
    int i = blockIdx.x * 256 + threadIdx.x;
    if (i >= Bt * ALLT) return;
    int co = i % ALLT;
    int b = i / ALLT;
    float sl1 = 0.f;
    for (int hx = 0; hx < 32; ++hx) sl1 += l1w[hx];
    const float* tp = T + (size_t)b * ALLT * 3;
    const float* wp = cvw + (size_t)co * ALLT * 3;
    float s = 0.f;
    for (int q = 0; q < ALLT * 3; ++q) s += tp[q] * wp[q];
    out[i] = s + cvb[co] * sl1 + l1b[0];
}

// ---------------- K12: projection + denorm, last PRED steps ----------------
__global__ __launch_bounds__(256) void k_dec(const float* __restrict__ enc,
                                             const float* __restrict__ pw,
                                             const float* __restrict__ pb,
                                             const float* __restrict__ mean,
                                             const float* __restrict__ stdv,
                                             float* __restrict__ out) {
    int i = blockIdx.x * 256 + threadIdx.x;
    if (i >= Bt * PRED * CIN) return;
    int c = i % CIN;
    int rest = i / CIN;
    int tt = rest % PRED;
    int b = rest / PRED;
    const float* e = enc + ((size_t)b * ALLT + SEQ + tt) * DM;
    const float* w = pw + c * DM;
    float s = pb[c];
    for (int d = 0; d < DM; ++d) s += e[d] * w[d];
    out[i] = s * stdv[b * CIN + c] + mean[b * CIN + c];
}

extern "C" void kernel_launch(void* const* d_in, const int* in_sizes, int n_in,
                              void* d_out, int out_size, void* d_ws, size_t ws_size,
                              hipStream_t stream) {
    (void)in_sizes; (void)n_in; (void)out_size;
    const float* x_enc  = (const float*)d_in[0];
    const float* x_mark = (const float*)d_in[1];
    const float* tok_w  = (const float*)d_in[4];
    const float* temp_w = (const float*)d_in[5];
    const float* pl_w   = (const float*)d_in[6];
    const float* pl_b   = (const float*)d_in[7];
    const float* ln_g   = (const float*)d_in[8];
    const float* ln_b   = (const float*)d_in[9];
    const float* c0_wr  = (const float*)d_in[10];
    const float* c0_wi  = (const float*)d_in[11];
    const float* c0_br  = (const float*)d_in[12];
    const float* c0_bi  = (const float*)d_in[13];
    const float* cA_wr  = (const float*)d_in[14];
    const float* cA_wi  = (const float*)d_in[15];
    const float* cA_br  = (const float*)d_in[16];
    const float* cA_bi  = (const float*)d_in[17];
    const float* cB_wr  = (const float*)d_in[18];
    const float* cB_wi  = (const float*)d_in[19];
    const float* cB_br  = (const float*)d_in[20];
    const float* cB_bi  = (const float*)d_in[21];
    const float* l0_w   = (const float*)d_in[22];
    const float* l0_b   = (const float*)d_in[23];
    const float* l2_w   = (const float*)d_in[24];
    const float* l2_b   = (const float*)d_in[25];
    const float* cv_w   = (const float*)d_in[26];
    const float* cv_b   = (const float*)d_in[27];
    const float* l1_w   = (const float*)d_in[28];
    const float* l1_b   = (const float*)d_in[29];
    const float* proj_w = (const float*)d_in[30];
    const float* proj_b = (const float*)d_in[31];

    float* out0 = (float*)d_out;                    // dec: [32,336,7]
    float* out1 = out0 + (size_t)Bt * PRED * CIN;   // seq_series: [32,672]

    float* ws = (float*)d_ws;
    size_t off = 0;
    float* enc  = ws + off; off += (size_t)Bt * ALLT * DM;
    float* enc0 = ws + off; off += (size_t)Bt * SEQ * DM;
    float* mean = ws + off; off += 256;
    float* stdv = ws + off; off += 256;
    short* wtbuf = (short*)(ws + off); off += 622592;   // 1,245,184 bf16 packed weights

    const size_t perb = (size_t)DM * NFFT * NF;  // 348,160
    int Bc = 32;
    while (Bc > 1) {
        size_t need = (off + (size_t)Bc * DM * NF + 3 * (size_t)Bc * perb) * sizeof(float);
        if (need <= ws_size) break;
        Bc >>= 1;
    }
    float* y2 = ws + off; off += (size_t)Bc * DM * NF;
    float* yfull = ws + off; off += (size_t)Bc * perb;
    int*   Apk = (int*)(ws + off); off += (size_t)Bc * perb;
    int*   Hpk = (int*)(ws + off); off += (size_t)Bc * perb;
    float* Tb = enc0;   // reuse: enc0 dead after k_plin2

    k_stats<<<Bt * CIN, 64, 0, stream>>>(x_enc, mean, stdv);
    k_wprep<<<(1245184 + 255) / 256, 256, 0, stream>>>(cA_wr, cA_wi, cB_wr, cB_wi,
                                                       c0_wr, c0_wi, wtbuf);
    k_embed<<<(Bt * SEQ * DM + 255) / 256, 256, 0, stream>>>(x_enc, x_mark, tok_w, temp_w,
                                                             mean, stdv, enc0);
    k_plin2<<<Bt * 14, 256, 0, stream>>>(enc0, pl_w, pl_b, enc);

    for (int l = 0; l < 2; ++l) {
        for (int b0 = 0; b0 < Bt; b0 += Bc) {
            k_stqka<<<Bc * 64, 256, 0, stream>>>(enc, b0, Apk);
            k_c0m<<<Bc * 64, 256, 0, stream>>>(Apk, wtbuf + 1179648 + (size_t)l * 32768,
                                               c0_br + l * 64, c0_bi + l * 64,
                                               l0_w + l * 2, yfull);
            for (int k = 1; k <= 2; ++k) {
                int convA = l * 4 + (k - 1) * 2;
                size_t boff = ((size_t)l * 2 + (k - 1)) * 64;
                k_conv3p<<<Bc * 64, 256, 0, stream>>>(Apk, wtbuf + (size_t)convA * 147456,
                                                      cA_br + boff, cA_bi + boff, k, 0,
                                                      l0_w + l * 2, Hpk, yfull);
                k_conv3p<<<Bc * 64, 256, 0, stream>>>(Hpk, wtbuf + (size_t)(convA + 1) * 147456,
                                                      cB_br + boff, cB_bi + boff, k, 1,
                                                      l0_w + l * 2, Hpk, yfull);
            }
            k_reduce2<<<Bc * 64, 256, 0, stream>>>(yfull, l0_b + l, y2);
            k_l2ln<<<Bc * ALLT, 64, 0, stream>>>(y2, l2_w + (size_t)l * ALLT * NF,
                                                 l2_b + (size_t)l * ALLT, ln_g, ln_b, enc, b0);
        }
    }

    k_T<<<(Bt * ALLT * 3 + 255) / 256, 256, 0, stream>>>(enc, l1_w, Tb);
    k_seq<<<(Bt * ALLT + 255) / 256, 256, 0, stream>>>(Tb, cv_w, cv_b, l1_w, l1_b, out1);
    k_dec<<<(Bt * PRED * CIN + 255) / 256, 256, 0, stream>>>(enc, proj_w, proj_b, mean, stdv, out0);
}